// Round 8
// baseline (711.263 us; speedup 1.0000x reference)
//
#include <hip/hip_runtime.h>
#include <cstdint>
#include <cstddef>

#define E_CNT 800000
#define N_CNT 50000
#define NT 6250  // tiles of 128 edges (4 waves x 32)

typedef short bf16x8 __attribute__((ext_vector_type(8)));
typedef short s16x4 __attribute__((ext_vector_type(4)));
typedef float f32x4 __attribute__((ext_vector_type(4)));
typedef uint32_t u32x4 __attribute__((ext_vector_type(4)));

// ws byte offsets
#define OFF_CURSOR 0
#define OFF_WFN 200064
#define OFF_WFC 241024
#define OFF_W2F 281984
#define OFF_BIASN 298368
#define OFF_BIASC 298880
#define OFF_SRC 299520
#define OFF_DST 3499520
#define OFF_DIST 6699520
#define OFF_HB 8299520
#define REQ_FULL 14699520

__device__ __forceinline__ short f2bf(float v) {
  uint32_t u = __builtin_bit_cast(uint32_t, v);
  u = (u + 0x7FFFu + ((u >> 16) & 1u)) >> 16;
  return (short)u;
}
__device__ __forceinline__ float bf2f(short s) {
  uint32_t u = ((uint32_t)(uint16_t)s) << 16;
  return __builtin_bit_cast(float, u);
}
__device__ __forceinline__ uint32_t pack2(float lo, float hi) {
  return ((uint32_t)(uint16_t)f2bf(hi) << 16) | (uint32_t)(uint16_t)f2bf(lo);
}
__device__ __forceinline__ float silu_f(float v) {
  return v * (1.0f / (1.0f + __expf(-v)));
}

// ---- prep: init (copy + bf16 h) | fragment-linear weights | histogram ----
// GEMM1 frags FEATURE-PERMUTED: frag col (nt, lane c) = true feature c*8+nt.
template <bool FULL>
__global__ void k_pre(const float* __restrict__ h, const float* __restrict__ x,
                      float* __restrict__ out, short* __restrict__ hb,
                      const int* __restrict__ eidx, int* __restrict__ cursor,
                      const float* __restrict__ W1n, const float* __restrict__ W1c,
                      const float* __restrict__ We2, const float* __restrict__ bn1,
                      const float* __restrict__ bc1, const float* __restrict__ be2,
                      const float* __restrict__ Wn2,
                      short* __restrict__ Wfn, short* __restrict__ Wfc,
                      short* __restrict__ W2f, float* __restrict__ biasn,
                      float* __restrict__ biasc) {
  const int b = (int)blockIdx.x;
  if (b < 3272) {
    const int i = b * 256 + (int)threadIdx.x;
    if (i < 800000) {
      const f32x4 v = ((const f32x4*)h)[i];
      ((f32x4*)out)[i] = v;
      if (FULL) {
        s16x4 p;
#pragma unroll
        for (int j = 0; j < 4; ++j) p[j] = f2bf(v[j]);
        *(s16x4*)(hb + i * 4) = p;
      }
    } else if (i < 837500) {
      ((f32x4*)out)[i] = ((const f32x4*)x)[i - 800000];
    }
  } else if (b < 3297) {
    const int idx = (b - 3272) * 4 + ((int)threadIdx.x >> 6);
    const int l = (int)threadIdx.x & 63;
    if (idx < 80) {
      const int fid = (idx < 40) ? idx : (idx - 40);
      const float* W1 = (idx < 40) ? W1n : W1c;
      short* Wf = (idx < 40) ? Wfn : Wfc;
      const int kt = fid >> 3, nt = fid & 7;
      const int feat = (l & 15) * 8 + nt;  // permuted feature mapping
      const int k0 = kt * 32 + (l >> 4) * 8;
      bf16x8 v;
#pragma unroll
      for (int j = 0; j < 8; ++j) {
        const int k = k0 + j;
        float val;
        if (k < 128) {
          val = W1[k * 128 + feat];
        } else {
          float s = 0.f;
          for (int cc = 0; cc < 32; ++cc)
            s = fmaf(We2[(k - 128) * 32 + cc], W1[(128 + cc) * 128 + feat], s);
          val = s;
        }
        v[j] = f2bf(val);
      }
      *(bf16x8*)&Wf[(fid * 64 + l) * 8] = v;
    } else if (idx < 96) {
      const int fid = idx - 80;
      const int kt2 = fid >> 2, nt2 = fid & 3;
      bf16x8 v;
#pragma unroll
      for (int j = 0; j < 8; ++j)
        v[j] = f2bf(Wn2[(kt2 * 32 + (l >> 4) * 8 + j) * 64 + nt2 * 16 + (l & 15)]);
      *(bf16x8*)&W2f[(fid * 64 + l) * 8] = v;
    } else if (idx == 96) {
      for (int col = l; col < 128; col += 64) {
        float sn = bn1[col], sc = bc1[col];
        for (int cc = 0; cc < 32; ++cc) {
          sn = fmaf(be2[cc], W1n[(128 + cc) * 128 + col], sn);
          sc = fmaf(be2[cc], W1c[(128 + cc) * 128 + col], sc);
        }
        biasn[col] = sn;
        biasc[col] = sc;
      }
    }
  } else if (FULL) {
    const int e = (b - 3297) * 256 + (int)threadIdx.x;
    if (e < E_CNT) atomicAdd(&cursor[eidx[E_CNT + e]], 1);
  }
}

__global__ __launch_bounds__(1024) void k_scan(int* __restrict__ cursor) {
  __shared__ int part[1024];
  const int t = (int)threadIdx.x;
  const int b0 = t * 49;
  int n = N_CNT - b0;
  n = n < 0 ? 0 : (n > 49 ? 49 : n);
  int s = 0;
  for (int i = 0; i < n; ++i) s += cursor[b0 + i];
  part[t] = s;
  __syncthreads();
  for (int off = 1; off < 1024; off <<= 1) {
    const int u = (t >= off) ? part[t - off] : 0;
    __syncthreads();
    part[t] += u;
    __syncthreads();
  }
  int run = (t == 0) ? 0 : part[t - 1];
  for (int i = 0; i < n; ++i) {
    const int old = cursor[b0 + i];
    cursor[b0 + i] = run;
    run += old;
  }
}

__global__ void k_fill(const int* __restrict__ eidx, const float* __restrict__ edist,
                       int* __restrict__ cursor, int* __restrict__ src_s,
                       int* __restrict__ dst_s, short* __restrict__ dist_s) {
  const int e = (int)(blockIdx.x * 256 + threadIdx.x);
  if (e < E_CNT) {
    const int d = eidx[E_CNT + e];
    const int pos = atomicAdd(&cursor[d], 1);
    src_s[pos] = eidx[e];
    dst_s[pos] = d;
    dist_s[pos] = f2bf(edist[e]);
  }
}

// ---- fused per-tile node+coord: shared gathers/A-operands ----
template <bool FULL>
__global__ __launch_bounds__(256, 2) void k_main(
    const float* __restrict__ h, const short* __restrict__ hb,
    const float* __restrict__ x, const float* __restrict__ edist,
    const float* __restrict__ We1, const float* __restrict__ be1,
    const float* __restrict__ bn2, const float* __restrict__ Wc2,
    const int* __restrict__ eidx,
    const int* __restrict__ src_s, const int* __restrict__ dst_s,
    const short* __restrict__ dist_s,
    const short* __restrict__ Wfn, const short* __restrict__ Wfc,
    const short* __restrict__ W2f,
    const float* __restrict__ biasn, const float* __restrict__ biasc,
    float* __restrict__ out, float* __restrict__ xo) {
  __shared__ __align__(16) short scr[4][16 * 136];

  const int tid = (int)threadIdx.x;
  const int w = tid >> 6, l = tid & 63, g = l >> 4, c = l & 15;
  short* myscr = &scr[w][0];

  float we1s[8], be1s[8];
#pragma unroll
  for (int j = 0; j < 8; ++j) { we1s[j] = We1[g * 8 + j]; be1s[j] = be1[g * 8 + j]; }
  float b1n[8], b1c[8], wc2l[8];  // permuted: lane owns true feats c*8..c*8+7
#pragma unroll
  for (int nt = 0; nt < 8; ++nt) {
    b1n[nt] = biasn[c * 8 + nt];
    b1c[nt] = biasc[c * 8 + nt];
    wc2l[nt] = Wc2[c * 8 + nt];
  }
  float bias2[4];
#pragma unroll
  for (int nt = 0; nt < 4; ++nt) bias2[nt] = bn2[nt * 16 + c];

  const f32x4 vzero = {0.f, 0.f, 0.f, 0.f};

  for (int t = (int)blockIdx.x; t < NT; t += (int)gridDim.x) {
    const short* wfn = Wfn;
    const short* wfc = Wfc;
    const short* w2t = W2f;
    asm volatile("" : "+v"(wfn), "+v"(wfc), "+v"(w2t));

    const int base = t * 128 + w * 32;
    // tile-row remap: A-row c, parity mt <-> edge base + 2*c + mt
    const int e0 = base + 2 * c, e1 = e0 + 1;
    int s0, s1, d0, d1;
    float dd0, dd1;
    if (FULL) {
      s0 = src_s[e0]; s1 = src_s[e1];
      d0 = dst_s[e0]; d1 = dst_s[e1];
      dd0 = bf2f(dist_s[e0]); dd1 = bf2f(dist_s[e1]);
    } else {
      s0 = eidx[e0]; s1 = eidx[e1];
      d0 = eidx[E_CNT + e0]; d1 = eidx[E_CNT + e1];
      dd0 = edist[e0]; dd1 = edist[e1];
    }

    // gather A once, hold in registers (shared by both GEMMs)
    bf16x8 ah0[4], ah1[4], ae0, ae1;
#pragma unroll
    for (int kt = 0; kt < 4; ++kt) {
      const size_t r0 = (size_t)((kt < 2) ? s0 : d0) * 64 + (kt & 1) * 32 + g * 8;
      const size_t r1 = (size_t)((kt < 2) ? s1 : d1) * 64 + (kt & 1) * 32 + g * 8;
      if (FULL) {
        ah0[kt] = *(const bf16x8*)&hb[r0];
        ah1[kt] = *(const bf16x8*)&hb[r1];
      } else {
        const f32x4 pa = *(const f32x4*)(h + r0), pb = *(const f32x4*)(h + r0 + 4);
        const f32x4 qa = *(const f32x4*)(h + r1), qb = *(const f32x4*)(h + r1 + 4);
        u32x4 u0 = {pack2(pa[0], pa[1]), pack2(pa[2], pa[3]),
                    pack2(pb[0], pb[1]), pack2(pb[2], pb[3])};
        u32x4 u1 = {pack2(qa[0], qa[1]), pack2(qa[2], qa[3]),
                    pack2(qb[0], qb[1]), pack2(qb[2], qb[3])};
        ah0[kt] = __builtin_bit_cast(bf16x8, u0);
        ah1[kt] = __builtin_bit_cast(bf16x8, u1);
      }
    }
    {
      float t0[8], t1[8];
#pragma unroll
      for (int j = 0; j < 8; ++j) {
        t0[j] = silu_f(fmaf(dd0, we1s[j], be1s[j]));
        t1[j] = silu_f(fmaf(dd1, we1s[j], be1s[j]));
      }
      u32x4 u0 = {pack2(t0[0], t0[1]), pack2(t0[2], t0[3]),
                  pack2(t0[4], t0[5]), pack2(t0[6], t0[7])};
      u32x4 u1 = {pack2(t1[0], t1[1]), pack2(t1[2], t1[3]),
                  pack2(t1[4], t1[5]), pack2(t1[6], t1[7])};
      ae0 = __builtin_bit_cast(bf16x8, u0);
      ae1 = __builtin_bit_cast(bf16x8, u1);
    }

    f32x4 acc[2][8];
#pragma unroll
    for (int mt = 0; mt < 2; ++mt)
#pragma unroll
      for (int nt = 0; nt < 8; ++nt) acc[mt][nt] = vzero;

    // ---- GEMM1 (node weights) ----
#pragma unroll
    for (int kt = 0; kt < 5; ++kt) {
      const bf16x8 a0 = (kt < 4) ? ah0[kt] : ae0;
      const bf16x8 a1 = (kt < 4) ? ah1[kt] : ae1;
#pragma unroll
      for (int nt = 0; nt < 8; ++nt) {
        const bf16x8 b = *(const bf16x8*)&wfn[(((kt << 3) + nt) << 9) + (l << 3)];
        acc[0][nt] = __builtin_amdgcn_mfma_f32_16x16x32_bf16(a0, b, acc[0][nt], 0, 0, 0);
        acc[1][nt] = __builtin_amdgcn_mfma_f32_16x16x32_bf16(a1, b, acc[1][nt], 0, 0, 0);
      }
    }

    // ---- node epilogue: per mt, silu->scr (b128), GEMM2, RLE atomics ----
#pragma unroll
    for (int mt = 0; mt < 2; ++mt) {
#pragma unroll
      for (int r = 0; r < 4; ++r) {
        const float v0 = silu_f(acc[mt][0][r] + b1n[0]);
        const float v1 = silu_f(acc[mt][1][r] + b1n[1]);
        const float v2 = silu_f(acc[mt][2][r] + b1n[2]);
        const float v3 = silu_f(acc[mt][3][r] + b1n[3]);
        const float v4 = silu_f(acc[mt][4][r] + b1n[4]);
        const float v5 = silu_f(acc[mt][5][r] + b1n[5]);
        const float v6 = silu_f(acc[mt][6][r] + b1n[6]);
        const float v7 = silu_f(acc[mt][7][r] + b1n[7]);
        u32x4 pkv = {pack2(v0, v1), pack2(v2, v3), pack2(v4, v5), pack2(v6, v7)};
        *(u32x4*)&myscr[(4 * g + r) * 136 + c * 8] = pkv;
      }

      f32x4 acc2[4];
#pragma unroll
      for (int nt2 = 0; nt2 < 4; ++nt2) acc2[nt2] = vzero;
#pragma unroll
      for (int kt2 = 0; kt2 < 4; ++kt2) {
        const bf16x8 a2 = *(const bf16x8*)&myscr[c * 136 + kt2 * 32 + g * 8];
#pragma unroll
        for (int nt2 = 0; nt2 < 4; ++nt2) {
          const bf16x8 b2 = *(const bf16x8*)&w2t[(((kt2 << 2) + nt2) << 9) + (l << 3)];
          acc2[nt2] = __builtin_amdgcn_mfma_f32_16x16x32_bf16(a2, b2, acc2[nt2], 0, 0, 0);
        }
      }

      const int dmt = mt ? d1 : d0;
      int des[4];
#pragma unroll
      for (int r = 0; r < 4; ++r) des[r] = __shfl(dmt, 4 * g + r);
      float run[4];
      int cur = des[0];
#pragma unroll
      for (int nt2 = 0; nt2 < 4; ++nt2) run[nt2] = acc2[nt2][0] + bias2[nt2];
#pragma unroll
      for (int s = 1; s < 4; ++s) {
        if (des[s] == cur) {
#pragma unroll
          for (int nt2 = 0; nt2 < 4; ++nt2) run[nt2] += acc2[nt2][s] + bias2[nt2];
        } else {
#pragma unroll
          for (int nt2 = 0; nt2 < 4; ++nt2)
            unsafeAtomicAdd(&out[(size_t)cur * 64 + nt2 * 16 + c], run[nt2]);
          cur = des[s];
#pragma unroll
          for (int nt2 = 0; nt2 < 4; ++nt2) run[nt2] = acc2[nt2][s] + bias2[nt2];
        }
      }
#pragma unroll
      for (int nt2 = 0; nt2 < 4; ++nt2)
        unsafeAtomicAdd(&out[(size_t)cur * 64 + nt2 * 16 + c], run[nt2]);
    }

    // ---- GEMM1 (coord weights), A reused from registers ----
#pragma unroll
    for (int mt = 0; mt < 2; ++mt)
#pragma unroll
      for (int nt = 0; nt < 8; ++nt) acc[mt][nt] = vzero;
#pragma unroll
    for (int kt = 0; kt < 5; ++kt) {
      const bf16x8 a0 = (kt < 4) ? ah0[kt] : ae0;
      const bf16x8 a1 = (kt < 4) ? ah1[kt] : ae1;
#pragma unroll
      for (int nt = 0; nt < 8; ++nt) {
        const bf16x8 b = *(const bf16x8*)&wfc[(((kt << 3) + nt) << 9) + (l << 3)];
        acc[0][nt] = __builtin_amdgcn_mfma_f32_16x16x32_bf16(a0, b, acc[0][nt], 0, 0, 0);
        acc[1][nt] = __builtin_amdgcn_mfma_f32_16x16x32_bf16(a1, b, acc[1][nt], 0, 0, 0);
      }
    }

    // ---- coord epilogue ----
    float p0[4], p1[4];
#pragma unroll
    for (int r = 0; r < 4; ++r) {
      float a = 0.f, bsum = 0.f;
#pragma unroll
      for (int nt = 0; nt < 8; ++nt) {
        a += silu_f(acc[0][nt][r] + b1c[nt]) * wc2l[nt];
        bsum += silu_f(acc[1][nt][r] + b1c[nt]) * wc2l[nt];
      }
      p0[r] = a; p1[r] = bsum;
    }
#pragma unroll
    for (int m = 1; m < 16; m <<= 1)
#pragma unroll
      for (int r = 0; r < 4; ++r) {
        p0[r] += __shfl_xor(p0[r], m);
        p1[r] += __shfl_xor(p1[r], m);
      }
    // every lane of group g now holds cw for its 8 consecutive edges
    const int mt = c & 1, rr = c >> 1;  // lane c<8 handles edge base+8g+c
    const int dA = __shfl(d0, 4 * g + rr), dB = __shfl(d1, 4 * g + rr);
    const int sA = __shfl(s0, 4 * g + rr), sB = __shfl(s1, 4 * g + rr);
    const int dstE = mt ? dB : dA;
    const int srcE = mt ? sB : sA;
    if (c < 8) {
      const float cwp0 = (rr == 0) ? p0[0] : (rr == 1) ? p0[1] : (rr == 2) ? p0[2] : p0[3];
      const float cwp1 = (rr == 0) ? p1[0] : (rr == 1) ? p1[1] : (rr == 2) ? p1[2] : p1[3];
      const float cw = mt ? cwp1 : cwp0;
      const float ax = x[srcE * 3 + 0] - x[dstE * 3 + 0];
      const float ay = x[srcE * 3 + 1] - x[dstE * 3 + 1];
      const float az = x[srcE * 3 + 2] - x[dstE * 3 + 2];
      float len = sqrtf(fmaf(ax, ax, fmaf(ay, ay, az * az)));
      len = fmaxf(len, 1e-8f);
      const float scl = cw / len;
      float vx = scl * ax, vy = scl * ay, vz = scl * az;
      // segmented inclusive scan over the 8 lanes (runs of equal dst, sorted)
#pragma unroll
      for (int k = 1; k < 8; k <<= 1) {
        const float tx = __shfl(vx, l - k);
        const float ty = __shfl(vy, l - k);
        const float tz = __shfl(vz, l - k);
        const int td = __shfl(dstE, l - k);
        if (c >= k && td == dstE) { vx += tx; vy += ty; vz += tz; }
      }
      const int dnx = __shfl(dstE, l + 1);
      if (c == 7 || dnx != dstE) {
        unsafeAtomicAdd(&xo[dstE * 3 + 0], vx);
        unsafeAtomicAdd(&xo[dstE * 3 + 1], vy);
        unsafeAtomicAdd(&xo[dstE * 3 + 2], vz);
      }
    }
  }
}

extern "C" void kernel_launch(void* const* d_in, const int* in_sizes, int n_in,
                              void* d_out, int out_size, void* d_ws, size_t ws_size,
                              hipStream_t stream) {
  const float* h = (const float*)d_in[0];
  const float* x = (const float*)d_in[1];
  const float* edist = (const float*)d_in[2];
  const float* We1 = (const float*)d_in[3];
  const float* be1 = (const float*)d_in[4];
  const float* We2 = (const float*)d_in[5];
  const float* be2 = (const float*)d_in[6];
  const float* Wn1 = (const float*)d_in[7];
  const float* bn1 = (const float*)d_in[8];
  const float* Wn2 = (const float*)d_in[9];
  const float* bn2 = (const float*)d_in[10];
  const float* Wc1 = (const float*)d_in[11];
  const float* bc1 = (const float*)d_in[12];
  const float* Wc2 = (const float*)d_in[13];
  const int* eidx = (const int*)d_in[14];
  float* out = (float*)d_out;
  float* xo = out + 3200000;

  char* wsb = (char*)d_ws;
  int* cursor = (int*)(wsb + OFF_CURSOR);
  short* Wfn = (short*)(wsb + OFF_WFN);
  short* Wfc = (short*)(wsb + OFF_WFC);
  short* W2f = (short*)(wsb + OFF_W2F);
  float* biasn = (float*)(wsb + OFF_BIASN);
  float* biasc = (float*)(wsb + OFF_BIASC);
  int* src_s = (int*)(wsb + OFF_SRC);
  int* dst_s = (int*)(wsb + OFF_DST);
  short* dist_s = (short*)(wsb + OFF_DIST);
  short* hb = (short*)(wsb + OFF_HB);

  const bool full = (ws_size >= (size_t)REQ_FULL);

  if (full) {
    hipMemsetAsync(cursor, 0, N_CNT * sizeof(int), stream);
    k_pre<true><<<dim3(6422), dim3(256), 0, stream>>>(h, x, out, hb, eidx, cursor,
                                                      Wn1, Wc1, We2, bn1, bc1, be2, Wn2,
                                                      Wfn, Wfc, W2f, biasn, biasc);
    k_scan<<<dim3(1), dim3(1024), 0, stream>>>(cursor);
    k_fill<<<dim3(3125), dim3(256), 0, stream>>>(eidx, edist, cursor, src_s, dst_s, dist_s);
    k_main<true><<<dim3(512), dim3(256), 0, stream>>>(
        h, hb, x, edist, We1, be1, bn2, Wc2, eidx, src_s, dst_s, dist_s,
        Wfn, Wfc, W2f, biasn, biasc, out, xo);
  } else {
    k_pre<false><<<dim3(3297), dim3(256), 0, stream>>>(h, x, out, nullptr, eidx, nullptr,
                                                       Wn1, Wc1, We2, bn1, bc1, be2, Wn2,
                                                       Wfn, Wfc, W2f, biasn, biasc);
    k_main<false><<<dim3(512), dim3(256), 0, stream>>>(
        h, nullptr, x, edist, We1, be1, bn2, Wc2, eidx, nullptr, nullptr, nullptr,
        Wfn, Wfc, W2f, biasn, biasc, out, xo);
  }
}

// Round 9
// 503.177 us; speedup vs baseline: 1.4135x; 1.4135x over previous
//
#include <hip/hip_runtime.h>
#include <cstdint>
#include <cstddef>

#define E_CNT 800000
#define N_CNT 50000
#define NT 6250  // tiles of 128 edges (4 waves x 32)

typedef short bf16x8 __attribute__((ext_vector_type(8)));
typedef short s16x4 __attribute__((ext_vector_type(4)));
typedef float f32x4 __attribute__((ext_vector_type(4)));
typedef uint32_t u32x4 __attribute__((ext_vector_type(4)));

// ws byte offsets
#define OFF_CURSOR 0
#define OFF_WFN 200064
#define OFF_WFC 241024
#define OFF_W2F 281984
#define OFF_BIASN 298368
#define OFF_BIASC 298880
#define OFF_SRC 299520
#define OFF_DST 3499520
#define OFF_DIST 6699520
#define OFF_HB 8299520
#define REQ_FULL 14699520

__device__ __forceinline__ short f2bf(float v) {
  uint32_t u = __builtin_bit_cast(uint32_t, v);
  u = (u + 0x7FFFu + ((u >> 16) & 1u)) >> 16;
  return (short)u;
}
__device__ __forceinline__ float bf2f(short s) {
  uint32_t u = ((uint32_t)(uint16_t)s) << 16;
  return __builtin_bit_cast(float, u);
}
__device__ __forceinline__ uint32_t pack2(float lo, float hi) {
  return ((uint32_t)(uint16_t)f2bf(hi) << 16) | (uint32_t)(uint16_t)f2bf(lo);
}
// HW packed f32->bf16 (RNE), 1 instr per 2 values (no builtin on gfx950)
__device__ __forceinline__ uint32_t cvtpk(float lo, float hi) {
  uint32_t r;
  asm("v_cvt_pk_bf16_f32 %0, %1, %2" : "=v"(r) : "v"(lo), "v"(hi));
  return r;
}
__device__ __forceinline__ float silu_f(float v) {
  return v * (1.0f / (1.0f + __expf(-v)));
}

// ---- prep: init (copy + bf16 h) | fragment-linear weights | histogram ----
// GEMM1 frags FEATURE-PERMUTED: frag col (nt, lane c) = true feature c*8+nt.
template <bool FULL>
__global__ void k_pre(const float* __restrict__ h, const float* __restrict__ x,
                      float* __restrict__ out, short* __restrict__ hb,
                      const int* __restrict__ eidx, int* __restrict__ cursor,
                      const float* __restrict__ W1n, const float* __restrict__ W1c,
                      const float* __restrict__ We2, const float* __restrict__ bn1,
                      const float* __restrict__ bc1, const float* __restrict__ be2,
                      const float* __restrict__ Wn2,
                      short* __restrict__ Wfn, short* __restrict__ Wfc,
                      short* __restrict__ W2f, float* __restrict__ biasn,
                      float* __restrict__ biasc) {
  const int b = (int)blockIdx.x;
  if (b < 3272) {
    const int i = b * 256 + (int)threadIdx.x;
    if (i < 800000) {
      const f32x4 v = ((const f32x4*)h)[i];
      ((f32x4*)out)[i] = v;
      if (FULL) {
        s16x4 p;
#pragma unroll
        for (int j = 0; j < 4; ++j) p[j] = f2bf(v[j]);
        *(s16x4*)(hb + i * 4) = p;
      }
    } else if (i < 837500) {
      ((f32x4*)out)[i] = ((const f32x4*)x)[i - 800000];
    }
  } else if (b < 3297) {
    const int idx = (b - 3272) * 4 + ((int)threadIdx.x >> 6);
    const int l = (int)threadIdx.x & 63;
    if (idx < 80) {
      const int fid = (idx < 40) ? idx : (idx - 40);
      const float* W1 = (idx < 40) ? W1n : W1c;
      short* Wf = (idx < 40) ? Wfn : Wfc;
      const int kt = fid >> 3, nt = fid & 7;
      const int feat = (l & 15) * 8 + nt;  // permuted feature mapping
      const int k0 = kt * 32 + (l >> 4) * 8;
      bf16x8 v;
#pragma unroll
      for (int j = 0; j < 8; ++j) {
        const int k = k0 + j;
        float val;
        if (k < 128) {
          val = W1[k * 128 + feat];
        } else {
          float s = 0.f;
          for (int cc = 0; cc < 32; ++cc)
            s = fmaf(We2[(k - 128) * 32 + cc], W1[(128 + cc) * 128 + feat], s);
          val = s;
        }
        v[j] = f2bf(val);
      }
      *(bf16x8*)&Wf[(fid * 64 + l) * 8] = v;
    } else if (idx < 96) {
      const int fid = idx - 80;
      const int kt2 = fid >> 2, nt2 = fid & 3;
      bf16x8 v;
#pragma unroll
      for (int j = 0; j < 8; ++j)
        v[j] = f2bf(Wn2[(kt2 * 32 + (l >> 4) * 8 + j) * 64 + nt2 * 16 + (l & 15)]);
      *(bf16x8*)&W2f[(fid * 64 + l) * 8] = v;
    } else if (idx == 96) {
      for (int col = l; col < 128; col += 64) {
        float sn = bn1[col], sc = bc1[col];
        for (int cc = 0; cc < 32; ++cc) {
          sn = fmaf(be2[cc], W1n[(128 + cc) * 128 + col], sn);
          sc = fmaf(be2[cc], W1c[(128 + cc) * 128 + col], sc);
        }
        biasn[col] = sn;
        biasc[col] = sc;
      }
    }
  } else if (FULL) {
    const int e = (b - 3297) * 256 + (int)threadIdx.x;
    if (e < E_CNT) atomicAdd(&cursor[eidx[E_CNT + e]], 1);
  }
}

__global__ __launch_bounds__(1024) void k_scan(int* __restrict__ cursor) {
  __shared__ int part[1024];
  const int t = (int)threadIdx.x;
  const int b0 = t * 49;
  int n = N_CNT - b0;
  n = n < 0 ? 0 : (n > 49 ? 49 : n);
  int s = 0;
  for (int i = 0; i < n; ++i) s += cursor[b0 + i];
  part[t] = s;
  __syncthreads();
  for (int off = 1; off < 1024; off <<= 1) {
    const int u = (t >= off) ? part[t - off] : 0;
    __syncthreads();
    part[t] += u;
    __syncthreads();
  }
  int run = (t == 0) ? 0 : part[t - 1];
  for (int i = 0; i < n; ++i) {
    const int old = cursor[b0 + i];
    cursor[b0 + i] = run;
    run += old;
  }
}

__global__ void k_fill(const int* __restrict__ eidx, const float* __restrict__ edist,
                       int* __restrict__ cursor, int* __restrict__ src_s,
                       int* __restrict__ dst_s, short* __restrict__ dist_s) {
  const int e = (int)(blockIdx.x * 256 + threadIdx.x);
  if (e < E_CNT) {
    const int d = eidx[E_CNT + e];
    const int pos = atomicAdd(&cursor[d], 1);
    src_s[pos] = eidx[e];
    dst_s[pos] = d;
    dist_s[pos] = f2bf(edist[e]);
  }
}

// ---- node: r5 structure + permuted feats + cvt_pk + index prefetch ----
template <bool SORTED>
__global__ __launch_bounds__(256, 2) void k_node(
    const float* __restrict__ h, const short* __restrict__ hb,
    const float* __restrict__ edist,
    const float* __restrict__ We1, const float* __restrict__ be1,
    const float* __restrict__ bn2, const int* __restrict__ eidx,
    const int* __restrict__ src_s, const int* __restrict__ dst_s,
    const short* __restrict__ dist_s,
    const short* __restrict__ Wf, const short* __restrict__ W2f,
    const float* __restrict__ biasn, float* __restrict__ out) {
  __shared__ __align__(16) short scr[4][16 * 136];

  const int tid = (int)threadIdx.x;
  const int w = tid >> 6, l = tid & 63, g = l >> 4, c = l & 15;
  short* myscr = &scr[w][0];

  float we1s[8], be1s[8];
#pragma unroll
  for (int j = 0; j < 8; ++j) { we1s[j] = We1[g * 8 + j]; be1s[j] = be1[g * 8 + j]; }
  float bias1[8];  // permuted: lane owns true features c*8..c*8+7
#pragma unroll
  for (int nt = 0; nt < 8; ++nt) bias1[nt] = biasn[c * 8 + nt];
  float bias2[4];
#pragma unroll
  for (int nt = 0; nt < 4; ++nt) bias2[nt] = bn2[nt * 16 + c];

  const f32x4 vzero = {0.f, 0.f, 0.f, 0.f};
  const int stride = (int)gridDim.x;

  int t = (int)blockIdx.x;
  int ps0 = 0, ps1 = 0, pd0 = 0, pd1 = 0;
  float pdd0 = 0.f, pdd1 = 0.f;
  if (t < NT) {
    const int e0 = t * 128 + w * 32 + 2 * c, e1 = e0 + 1;
    if (SORTED) {
      ps0 = src_s[e0]; ps1 = src_s[e1];
      pd0 = dst_s[e0]; pd1 = dst_s[e1];
      pdd0 = bf2f(dist_s[e0]); pdd1 = bf2f(dist_s[e1]);
    } else {
      ps0 = eidx[e0]; ps1 = eidx[e1];
      pd0 = eidx[E_CNT + e0]; pd1 = eidx[E_CNT + e1];
      pdd0 = edist[e0]; pdd1 = edist[e1];
    }
  }

  for (; t < NT; t += stride) {
    const short* wft = Wf;
    const short* w2t = W2f;
    asm volatile("" : "+v"(wft), "+v"(w2t));

    const int s0 = ps0, s1 = ps1, d0 = pd0, d1 = pd1;
    const float dd0 = pdd0, dd1 = pdd1;

    // prefetch next tile's indices (hides index-load latency)
    const int tn = t + stride;
    if (tn < NT) {
      const int e0 = tn * 128 + w * 32 + 2 * c, e1 = e0 + 1;
      if (SORTED) {
        ps0 = src_s[e0]; ps1 = src_s[e1];
        pd0 = dst_s[e0]; pd1 = dst_s[e1];
        pdd0 = bf2f(dist_s[e0]); pdd1 = bf2f(dist_s[e1]);
      } else {
        ps0 = eidx[e0]; ps1 = eidx[e1];
        pd0 = eidx[E_CNT + e0]; pd1 = eidx[E_CNT + e1];
        pdd0 = edist[e0]; pdd1 = edist[e1];
      }
    }

    f32x4 acc[2][8];
#pragma unroll
    for (int mt = 0; mt < 2; ++mt)
#pragma unroll
      for (int nt = 0; nt < 8; ++nt) acc[mt][nt] = vzero;

#pragma unroll
    for (int kt = 0; kt < 5; ++kt) {
      bf16x8 a0, a1;
      if (kt < 4) {
        const size_t r0 = (size_t)((kt < 2) ? s0 : d0) * 64 + (kt & 1) * 32 + g * 8;
        const size_t r1 = (size_t)((kt < 2) ? s1 : d1) * 64 + (kt & 1) * 32 + g * 8;
        if (SORTED) {
          a0 = *(const bf16x8*)&hb[r0];
          a1 = *(const bf16x8*)&hb[r1];
        } else {
          const f32x4 pa = *(const f32x4*)(h + r0), pb = *(const f32x4*)(h + r0 + 4);
          const f32x4 qa = *(const f32x4*)(h + r1), qb = *(const f32x4*)(h + r1 + 4);
          u32x4 u0 = {pack2(pa[0], pa[1]), pack2(pa[2], pa[3]),
                      pack2(pb[0], pb[1]), pack2(pb[2], pb[3])};
          u32x4 u1 = {pack2(qa[0], qa[1]), pack2(qa[2], qa[3]),
                      pack2(qb[0], qb[1]), pack2(qb[2], qb[3])};
          a0 = __builtin_bit_cast(bf16x8, u0);
          a1 = __builtin_bit_cast(bf16x8, u1);
        }
      } else {
        float t0[8], t1[8];
#pragma unroll
        for (int j = 0; j < 8; ++j) {
          t0[j] = silu_f(fmaf(dd0, we1s[j], be1s[j]));
          t1[j] = silu_f(fmaf(dd1, we1s[j], be1s[j]));
        }
        u32x4 u0 = {cvtpk(t0[0], t0[1]), cvtpk(t0[2], t0[3]),
                    cvtpk(t0[4], t0[5]), cvtpk(t0[6], t0[7])};
        u32x4 u1 = {cvtpk(t1[0], t1[1]), cvtpk(t1[2], t1[3]),
                    cvtpk(t1[4], t1[5]), cvtpk(t1[6], t1[7])};
        a0 = __builtin_bit_cast(bf16x8, u0);
        a1 = __builtin_bit_cast(bf16x8, u1);
      }
#pragma unroll
      for (int nt = 0; nt < 8; ++nt) {
        const bf16x8 b = *(const bf16x8*)&wft[(((kt << 3) + nt) << 9) + (l << 3)];
        acc[0][nt] = __builtin_amdgcn_mfma_f32_16x16x32_bf16(a0, b, acc[0][nt], 0, 0, 0);
        acc[1][nt] = __builtin_amdgcn_mfma_f32_16x16x32_bf16(a1, b, acc[1][nt], 0, 0, 0);
      }
    }

    f32x4 acc2[2][4];
#pragma unroll
    for (int nt = 0; nt < 4; ++nt) { acc2[0][nt] = vzero; acc2[1][nt] = vzero; }

#pragma unroll
    for (int mt = 0; mt < 2; ++mt) {
      // silu + HW-packed bf16 -> one ds_write_b128 per output row
#pragma unroll
      for (int r = 0; r < 4; ++r) {
        const float v0 = silu_f(acc[mt][0][r] + bias1[0]);
        const float v1 = silu_f(acc[mt][1][r] + bias1[1]);
        const float v2 = silu_f(acc[mt][2][r] + bias1[2]);
        const float v3 = silu_f(acc[mt][3][r] + bias1[3]);
        const float v4 = silu_f(acc[mt][4][r] + bias1[4]);
        const float v5 = silu_f(acc[mt][5][r] + bias1[5]);
        const float v6 = silu_f(acc[mt][6][r] + bias1[6]);
        const float v7 = silu_f(acc[mt][7][r] + bias1[7]);
        u32x4 pkv = {cvtpk(v0, v1), cvtpk(v2, v3), cvtpk(v4, v5), cvtpk(v6, v7)};
        *(u32x4*)&myscr[(4 * g + r) * 136 + c * 8] = pkv;
      }
#pragma unroll
      for (int kt2 = 0; kt2 < 4; ++kt2) {
        const bf16x8 a2 = *(const bf16x8*)&myscr[c * 136 + kt2 * 32 + g * 8];
#pragma unroll
        for (int nt2 = 0; nt2 < 4; ++nt2) {
          const bf16x8 b2 = *(const bf16x8*)&w2t[(((kt2 << 2) + nt2) << 9) + (l << 3)];
          acc2[mt][nt2] = __builtin_amdgcn_mfma_f32_16x16x32_bf16(a2, b2, acc2[mt][nt2], 0, 0, 0);
        }
      }
    }

    // RLE over 8 consecutive (sorted) edges base+8g..+7
    int des[8];
#pragma unroll
    for (int s = 0; s < 8; ++s)
      des[s] = __shfl((s & 1) ? d1 : d0, 4 * g + (s >> 1));

    float run[4];
    int cur = des[0];
#pragma unroll
    for (int nt2 = 0; nt2 < 4; ++nt2) run[nt2] = acc2[0][nt2][0] + bias2[nt2];
#pragma unroll
    for (int s = 1; s < 8; ++s) {
      const int mt = s & 1, r = s >> 1;
      if (des[s] == cur) {
#pragma unroll
        for (int nt2 = 0; nt2 < 4; ++nt2) run[nt2] += acc2[mt][nt2][r] + bias2[nt2];
      } else {
#pragma unroll
        for (int nt2 = 0; nt2 < 4; ++nt2)
          unsafeAtomicAdd(&out[(size_t)cur * 64 + nt2 * 16 + c], run[nt2]);
        cur = des[s];
#pragma unroll
        for (int nt2 = 0; nt2 < 4; ++nt2) run[nt2] = acc2[mt][nt2][r] + bias2[nt2];
      }
    }
#pragma unroll
    for (int nt2 = 0; nt2 < 4; ++nt2)
      unsafeAtomicAdd(&out[(size_t)cur * 64 + nt2 * 16 + c], run[nt2]);
  }
}

// ---- coord: sorted + segmented-scan RLE epilogue + prefetch ----
template <bool SORTED>
__global__ __launch_bounds__(256, 2) void k_coord(
    const float* __restrict__ h, const short* __restrict__ hb,
    const float* __restrict__ x, const float* __restrict__ edist,
    const float* __restrict__ We1, const float* __restrict__ be1,
    const float* __restrict__ Wc2, const int* __restrict__ eidx,
    const int* __restrict__ src_s, const int* __restrict__ dst_s,
    const short* __restrict__ dist_s,
    const short* __restrict__ Wf, const float* __restrict__ biasc,
    float* __restrict__ xo) {
  const int tid = (int)threadIdx.x;
  const int w = tid >> 6, l = tid & 63, g = l >> 4, c = l & 15;

  float we1s[8], be1s[8];
#pragma unroll
  for (int j = 0; j < 8; ++j) { we1s[j] = We1[g * 8 + j]; be1s[j] = be1[g * 8 + j]; }
  float b1c[8], wc2l[8];  // permuted: lane owns true features c*8..c*8+7
#pragma unroll
  for (int nt = 0; nt < 8; ++nt) {
    b1c[nt] = biasc[c * 8 + nt];
    wc2l[nt] = Wc2[c * 8 + nt];
  }

  const f32x4 vzero = {0.f, 0.f, 0.f, 0.f};
  const int stride = (int)gridDim.x;

  int t = (int)blockIdx.x;
  int ps0 = 0, ps1 = 0, pd0 = 0, pd1 = 0;
  float pdd0 = 0.f, pdd1 = 0.f;
  if (t < NT) {
    const int e0 = t * 128 + w * 32 + 2 * c, e1 = e0 + 1;
    if (SORTED) {
      ps0 = src_s[e0]; ps1 = src_s[e1];
      pd0 = dst_s[e0]; pd1 = dst_s[e1];
      pdd0 = bf2f(dist_s[e0]); pdd1 = bf2f(dist_s[e1]);
    } else {
      ps0 = eidx[e0]; ps1 = eidx[e1];
      pd0 = eidx[E_CNT + e0]; pd1 = eidx[E_CNT + e1];
      pdd0 = edist[e0]; pdd1 = edist[e1];
    }
  }

  for (; t < NT; t += stride) {
    const short* wft = Wf;
    asm volatile("" : "+v"(wft));

    const int s0 = ps0, s1 = ps1, d0 = pd0, d1 = pd1;
    const float dd0 = pdd0, dd1 = pdd1;

    const int tn = t + stride;
    if (tn < NT) {
      const int e0 = tn * 128 + w * 32 + 2 * c, e1 = e0 + 1;
      if (SORTED) {
        ps0 = src_s[e0]; ps1 = src_s[e1];
        pd0 = dst_s[e0]; pd1 = dst_s[e1];
        pdd0 = bf2f(dist_s[e0]); pdd1 = bf2f(dist_s[e1]);
      } else {
        ps0 = eidx[e0]; ps1 = eidx[e1];
        pd0 = eidx[E_CNT + e0]; pd1 = eidx[E_CNT + e1];
        pdd0 = edist[e0]; pdd1 = edist[e1];
      }
    }

    f32x4 acc[2][8];
#pragma unroll
    for (int mt = 0; mt < 2; ++mt)
#pragma unroll
      for (int nt = 0; nt < 8; ++nt) acc[mt][nt] = vzero;

#pragma unroll
    for (int kt = 0; kt < 5; ++kt) {
      bf16x8 a0, a1;
      if (kt < 4) {
        const size_t r0 = (size_t)((kt < 2) ? s0 : d0) * 64 + (kt & 1) * 32 + g * 8;
        const size_t r1 = (size_t)((kt < 2) ? s1 : d1) * 64 + (kt & 1) * 32 + g * 8;
        if (SORTED) {
          a0 = *(const bf16x8*)&hb[r0];
          a1 = *(const bf16x8*)&hb[r1];
        } else {
          const f32x4 pa = *(const f32x4*)(h + r0), pb = *(const f32x4*)(h + r0 + 4);
          const f32x4 qa = *(const f32x4*)(h + r1), qb = *(const f32x4*)(h + r1 + 4);
          u32x4 u0 = {pack2(pa[0], pa[1]), pack2(pa[2], pa[3]),
                      pack2(pb[0], pb[1]), pack2(pb[2], pb[3])};
          u32x4 u1 = {pack2(qa[0], qa[1]), pack2(qa[2], qa[3]),
                      pack2(qb[0], qb[1]), pack2(qb[2], qb[3])};
          a0 = __builtin_bit_cast(bf16x8, u0);
          a1 = __builtin_bit_cast(bf16x8, u1);
        }
      } else {
        float t0[8], t1[8];
#pragma unroll
        for (int j = 0; j < 8; ++j) {
          t0[j] = silu_f(fmaf(dd0, we1s[j], be1s[j]));
          t1[j] = silu_f(fmaf(dd1, we1s[j], be1s[j]));
        }
        u32x4 u0 = {cvtpk(t0[0], t0[1]), cvtpk(t0[2], t0[3]),
                    cvtpk(t0[4], t0[5]), cvtpk(t0[6], t0[7])};
        u32x4 u1 = {cvtpk(t1[0], t1[1]), cvtpk(t1[2], t1[3]),
                    cvtpk(t1[4], t1[5]), cvtpk(t1[6], t1[7])};
        a0 = __builtin_bit_cast(bf16x8, u0);
        a1 = __builtin_bit_cast(bf16x8, u1);
      }
#pragma unroll
      for (int nt = 0; nt < 8; ++nt) {
        const bf16x8 b = *(const bf16x8*)&wft[(((kt << 3) + nt) << 9) + (l << 3)];
        acc[0][nt] = __builtin_amdgcn_mfma_f32_16x16x32_bf16(a0, b, acc[0][nt], 0, 0, 0);
        acc[1][nt] = __builtin_amdgcn_mfma_f32_16x16x32_bf16(a1, b, acc[1][nt], 0, 0, 0);
      }
    }

    // coord_w partials + 16-lane butterfly (all lanes end with all 8 values)
    float p0[4], p1[4];
#pragma unroll
    for (int r = 0; r < 4; ++r) {
      float a = 0.f, bsum = 0.f;
#pragma unroll
      for (int nt = 0; nt < 8; ++nt) {
        a += silu_f(acc[0][nt][r] + b1c[nt]) * wc2l[nt];
        bsum += silu_f(acc[1][nt][r] + b1c[nt]) * wc2l[nt];
      }
      p0[r] = a; p1[r] = bsum;
    }
#pragma unroll
    for (int m = 1; m < 16; m <<= 1)
#pragma unroll
      for (int r = 0; r < 4; ++r) {
        p0[r] += __shfl_xor(p0[r], m);
        p1[r] += __shfl_xor(p1[r], m);
      }

    // lane c<8 of each group handles edge base+8g+c (consecutive when sorted)
    const int mt = c & 1, rr = c >> 1;
    const int dA = __shfl(d0, 4 * g + rr), dB = __shfl(d1, 4 * g + rr);
    const int sA = __shfl(s0, 4 * g + rr), sB = __shfl(s1, 4 * g + rr);
    const int dstE = mt ? dB : dA;
    const int srcE = mt ? sB : sA;
    if (c < 8) {
      const float cwp0 = (rr == 0) ? p0[0] : (rr == 1) ? p0[1] : (rr == 2) ? p0[2] : p0[3];
      const float cwp1 = (rr == 0) ? p1[0] : (rr == 1) ? p1[1] : (rr == 2) ? p1[2] : p1[3];
      const float cw = mt ? cwp1 : cwp0;
      const float ax = x[srcE * 3 + 0] - x[dstE * 3 + 0];
      const float ay = x[srcE * 3 + 1] - x[dstE * 3 + 1];
      const float az = x[srcE * 3 + 2] - x[dstE * 3 + 2];
      float len = sqrtf(fmaf(ax, ax, fmaf(ay, ay, az * az)));
      len = fmaxf(len, 1e-8f);
      const float scl = cw / len;
      float vx = scl * ax, vy = scl * ay, vz = scl * az;
      // segmented inclusive scan over the 8 lanes (equal-dst runs, sorted)
#pragma unroll
      for (int k = 1; k < 8; k <<= 1) {
        const float tx = __shfl(vx, l - k);
        const float ty = __shfl(vy, l - k);
        const float tz = __shfl(vz, l - k);
        const int td = __shfl(dstE, l - k);
        if (c >= k && td == dstE) { vx += tx; vy += ty; vz += tz; }
      }
      const int dnx = __shfl(dstE, l + 1);
      if (c == 7 || dnx != dstE) {
        unsafeAtomicAdd(&xo[dstE * 3 + 0], vx);
        unsafeAtomicAdd(&xo[dstE * 3 + 1], vy);
        unsafeAtomicAdd(&xo[dstE * 3 + 2], vz);
      }
    }
  }
}

extern "C" void kernel_launch(void* const* d_in, const int* in_sizes, int n_in,
                              void* d_out, int out_size, void* d_ws, size_t ws_size,
                              hipStream_t stream) {
  const float* h = (const float*)d_in[0];
  const float* x = (const float*)d_in[1];
  const float* edist = (const float*)d_in[2];
  const float* We1 = (const float*)d_in[3];
  const float* be1 = (const float*)d_in[4];
  const float* We2 = (const float*)d_in[5];
  const float* be2 = (const float*)d_in[6];
  const float* Wn1 = (const float*)d_in[7];
  const float* bn1 = (const float*)d_in[8];
  const float* Wn2 = (const float*)d_in[9];
  const float* bn2 = (const float*)d_in[10];
  const float* Wc1 = (const float*)d_in[11];
  const float* bc1 = (const float*)d_in[12];
  const float* Wc2 = (const float*)d_in[13];
  const int* eidx = (const int*)d_in[14];
  float* out = (float*)d_out;
  float* xo = out + 3200000;

  char* wsb = (char*)d_ws;
  int* cursor = (int*)(wsb + OFF_CURSOR);
  short* Wfn = (short*)(wsb + OFF_WFN);
  short* Wfc = (short*)(wsb + OFF_WFC);
  short* W2f = (short*)(wsb + OFF_W2F);
  float* biasn = (float*)(wsb + OFF_BIASN);
  float* biasc = (float*)(wsb + OFF_BIASC);
  int* src_s = (int*)(wsb + OFF_SRC);
  int* dst_s = (int*)(wsb + OFF_DST);
  short* dist_s = (short*)(wsb + OFF_DIST);
  short* hb = (short*)(wsb + OFF_HB);

  const bool full = (ws_size >= (size_t)REQ_FULL);

  if (full) {
    hipMemsetAsync(cursor, 0, N_CNT * sizeof(int), stream);
    k_pre<true><<<dim3(6422), dim3(256), 0, stream>>>(h, x, out, hb, eidx, cursor,
                                                      Wn1, Wc1, We2, bn1, bc1, be2, Wn2,
                                                      Wfn, Wfc, W2f, biasn, biasc);
    k_scan<<<dim3(1), dim3(1024), 0, stream>>>(cursor);
    k_fill<<<dim3(3125), dim3(256), 0, stream>>>(eidx, edist, cursor, src_s, dst_s, dist_s);
    k_node<true><<<dim3(512), dim3(256), 0, stream>>>(h, hb, edist, We1, be1, bn2, eidx,
                                                      src_s, dst_s, dist_s, Wfn, W2f,
                                                      biasn, out);
    k_coord<true><<<dim3(512), dim3(256), 0, stream>>>(h, hb, x, edist, We1, be1, Wc2,
                                                       eidx, src_s, dst_s, dist_s,
                                                       Wfc, biasc, xo);
  } else {
    k_pre<false><<<dim3(3297), dim3(256), 0, stream>>>(h, x, out, nullptr, eidx, nullptr,
                                                       Wn1, Wc1, We2, bn1, bc1, be2, Wn2,
                                                       Wfn, Wfc, W2f, biasn, biasc);
    k_node<false><<<dim3(512), dim3(256), 0, stream>>>(h, nullptr, edist, We1, be1, bn2,
                                                       eidx, nullptr, nullptr, nullptr,
                                                       Wfn, W2f, biasn, out);
    k_coord<false><<<dim3(512), dim3(256), 0, stream>>>(h, nullptr, x, edist, We1, be1,
                                                        Wc2, eidx, nullptr, nullptr,
                                                        nullptr, Wfc, biasc, xo);
  }
}

// Round 11
// 492.374 us; speedup vs baseline: 1.4446x; 1.0219x over previous
//
#include <hip/hip_runtime.h>
#include <cstdint>
#include <cstddef>

#define E_CNT 800000
#define N_CNT 50000
#define NT 6250  // tiles of 128 edges (4 waves x 32)

typedef short bf16x8 __attribute__((ext_vector_type(8)));
typedef short s16x4 __attribute__((ext_vector_type(4)));
typedef float f32x4 __attribute__((ext_vector_type(4)));
typedef uint32_t u32x4 __attribute__((ext_vector_type(4)));

// ws byte offsets (identical to round-9 known-good layout)
#define OFF_CURSOR 0
#define OFF_WFN 200064
#define OFF_WFC 241024
#define OFF_W2F 281984
#define OFF_BIASN 298368
#define OFF_BIASC 298880
#define OFF_SRC 299520
#define OFF_DST 3499520
#define OFF_DIST 6699520
#define OFF_HB 8299520
#define REQ_FULL 14699520

__device__ __forceinline__ short f2bf(float v) {
  uint32_t u = __builtin_bit_cast(uint32_t, v);
  u = (u + 0x7FFFu + ((u >> 16) & 1u)) >> 16;
  return (short)u;
}
__device__ __forceinline__ float bf2f(short s) {
  uint32_t u = ((uint32_t)(uint16_t)s) << 16;
  return __builtin_bit_cast(float, u);
}
__device__ __forceinline__ uint32_t pack2(float lo, float hi) {
  return ((uint32_t)(uint16_t)f2bf(hi) << 16) | (uint32_t)(uint16_t)f2bf(lo);
}
// HW packed f32->bf16 (RNE), 1 instr per 2 values (no builtin on gfx950)
__device__ __forceinline__ uint32_t cvtpk(float lo, float hi) {
  uint32_t r;
  asm("v_cvt_pk_bf16_f32 %0, %1, %2" : "=v"(r) : "v"(lo), "v"(hi));
  return r;
}
__device__ __forceinline__ float silu_f(float v) {
  return v * (1.0f / (1.0f + __expf(-v)));
}

// ---- prep: init (copy + bf16 h) | fragment-linear weights | histogram ----
// GEMM1 frags FEATURE-PERMUTED: frag col (nt, lane c) = true feature c*8+nt.
template <bool FULL>
__global__ void k_pre(const float* __restrict__ h, const float* __restrict__ x,
                      float* __restrict__ out, short* __restrict__ hb,
                      const int* __restrict__ eidx, int* __restrict__ cursor,
                      const float* __restrict__ W1n, const float* __restrict__ W1c,
                      const float* __restrict__ We2, const float* __restrict__ bn1,
                      const float* __restrict__ bc1, const float* __restrict__ be2,
                      const float* __restrict__ Wn2,
                      short* __restrict__ Wfn, short* __restrict__ Wfc,
                      short* __restrict__ W2f, float* __restrict__ biasn,
                      float* __restrict__ biasc) {
  const int b = (int)blockIdx.x;
  if (b < 3272) {
    const int i = b * 256 + (int)threadIdx.x;
    if (i < 800000) {
      const f32x4 v = ((const f32x4*)h)[i];
      ((f32x4*)out)[i] = v;
      if (FULL) {
        s16x4 p;
#pragma unroll
        for (int j = 0; j < 4; ++j) p[j] = f2bf(v[j]);
        *(s16x4*)(hb + i * 4) = p;
      }
    } else if (i < 837500) {
      ((f32x4*)out)[i] = ((const f32x4*)x)[i - 800000];
    }
  } else if (b < 3297) {
    const int idx = (b - 3272) * 4 + ((int)threadIdx.x >> 6);
    const int l = (int)threadIdx.x & 63;
    if (idx < 80) {
      const int fid = (idx < 40) ? idx : (idx - 40);
      const float* W1 = (idx < 40) ? W1n : W1c;
      short* Wf = (idx < 40) ? Wfn : Wfc;
      const int kt = fid >> 3, nt = fid & 7;
      const int feat = (l & 15) * 8 + nt;  // permuted feature mapping
      const int k0 = kt * 32 + (l >> 4) * 8;
      bf16x8 v;
#pragma unroll
      for (int j = 0; j < 8; ++j) {
        const int k = k0 + j;
        float val;
        if (k < 128) {
          val = W1[k * 128 + feat];
        } else {
          float s = 0.f;
          for (int cc = 0; cc < 32; ++cc)
            s = fmaf(We2[(k - 128) * 32 + cc], W1[(128 + cc) * 128 + feat], s);
          val = s;
        }
        v[j] = f2bf(val);
      }
      *(bf16x8*)&Wf[(fid * 64 + l) * 8] = v;
    } else if (idx < 96) {
      const int fid = idx - 80;
      const int kt2 = fid >> 2, nt2 = fid & 3;
      bf16x8 v;
#pragma unroll
      for (int j = 0; j < 8; ++j)
        v[j] = f2bf(Wn2[(kt2 * 32 + (l >> 4) * 8 + j) * 64 + nt2 * 16 + (l & 15)]);
      *(bf16x8*)&W2f[(fid * 64 + l) * 8] = v;
    } else if (idx == 96) {
      for (int col = l; col < 128; col += 64) {
        float sn = bn1[col], sc = bc1[col];
        for (int cc = 0; cc < 32; ++cc) {
          sn = fmaf(be2[cc], W1n[(128 + cc) * 128 + col], sn);
          sc = fmaf(be2[cc], W1c[(128 + cc) * 128 + col], sc);
        }
        biasn[col] = sn;
        biasc[col] = sc;
      }
    }
  } else if (FULL) {
    const int e = (b - 3297) * 256 + (int)threadIdx.x;
    if (e < E_CNT) atomicAdd(&cursor[eidx[E_CNT + e]], 1);
  }
}

__global__ __launch_bounds__(1024) void k_scan(int* __restrict__ cursor) {
  __shared__ int part[1024];
  const int t = (int)threadIdx.x;
  const int b0 = t * 49;
  int n = N_CNT - b0;
  n = n < 0 ? 0 : (n > 49 ? 49 : n);
  int s = 0;
  for (int i = 0; i < n; ++i) s += cursor[b0 + i];
  part[t] = s;
  __syncthreads();
  for (int off = 1; off < 1024; off <<= 1) {
    const int u = (t >= off) ? part[t - off] : 0;
    __syncthreads();
    part[t] += u;
    __syncthreads();
  }
  int run = (t == 0) ? 0 : part[t - 1];
  for (int i = 0; i < n; ++i) {
    const int old = cursor[b0 + i];
    cursor[b0 + i] = run;
    run += old;
  }
}

__global__ void k_fill(const int* __restrict__ eidx, const float* __restrict__ edist,
                       int* __restrict__ cursor, int* __restrict__ src_s,
                       int* __restrict__ dst_s, short* __restrict__ dist_s) {
  const int e = (int)(blockIdx.x * 256 + threadIdx.x);
  if (e < E_CNT) {
    const int d = eidx[E_CNT + e];
    const int pos = atomicAdd(&cursor[d], 1);
    src_s[pos] = eidx[e];
    dst_s[pos] = d;
    dist_s[pos] = f2bf(edist[e]);
  }
}

// ---- fused main: blocks [0,half) = node path (r9 k_node body), blocks
// [half,2*half) = coord path (r9 k_coord body). grid = 512 so all blocks are
// co-resident (2/CU x 256 CU) -> the two latency-bound phases overlap.
template <bool SORTED>
__global__ __launch_bounds__(256, 2) void k_main(
    const float* __restrict__ h, const short* __restrict__ hb,
    const float* __restrict__ x, const float* __restrict__ edist,
    const float* __restrict__ We1, const float* __restrict__ be1,
    const float* __restrict__ bn2, const float* __restrict__ Wc2,
    const int* __restrict__ eidx,
    const int* __restrict__ src_s, const int* __restrict__ dst_s,
    const short* __restrict__ dist_s,
    const short* __restrict__ Wfn, const short* __restrict__ Wfc,
    const short* __restrict__ W2f,
    const float* __restrict__ biasn, const float* __restrict__ biasc,
    float* __restrict__ out, float* __restrict__ xo) {
  __shared__ __align__(16) short scr[4][16 * 136];

  const int tid = (int)threadIdx.x;
  const int w = tid >> 6, l = tid & 63, g = l >> 4, c = l & 15;
  const f32x4 vzero = {0.f, 0.f, 0.f, 0.f};
  const int half = (int)(gridDim.x >> 1);

  if ((int)blockIdx.x < half) {
    // ================= node path (r9 k_node, stride=half) =================
    short* myscr = &scr[w][0];

    float we1s[8], be1s[8];
#pragma unroll
    for (int j = 0; j < 8; ++j) { we1s[j] = We1[g * 8 + j]; be1s[j] = be1[g * 8 + j]; }
    float bias1[8];  // permuted: lane owns true features c*8..c*8+7
#pragma unroll
    for (int nt = 0; nt < 8; ++nt) bias1[nt] = biasn[c * 8 + nt];
    float bias2[4];
#pragma unroll
    for (int nt = 0; nt < 4; ++nt) bias2[nt] = bn2[nt * 16 + c];

    int t = (int)blockIdx.x;
    int ps0 = 0, ps1 = 0, pd0 = 0, pd1 = 0;
    float pdd0 = 0.f, pdd1 = 0.f;
    if (t < NT) {
      const int e0 = t * 128 + w * 32 + 2 * c, e1 = e0 + 1;
      if (SORTED) {
        ps0 = src_s[e0]; ps1 = src_s[e1];
        pd0 = dst_s[e0]; pd1 = dst_s[e1];
        pdd0 = bf2f(dist_s[e0]); pdd1 = bf2f(dist_s[e1]);
      } else {
        ps0 = eidx[e0]; ps1 = eidx[e1];
        pd0 = eidx[E_CNT + e0]; pd1 = eidx[E_CNT + e1];
        pdd0 = edist[e0]; pdd1 = edist[e1];
      }
    }

    for (; t < NT; t += half) {
      const short* wft = Wfn;
      const short* w2t = W2f;
      asm volatile("" : "+v"(wft), "+v"(w2t));

      const int s0 = ps0, s1 = ps1, d0 = pd0, d1 = pd1;
      const float dd0 = pdd0, dd1 = pdd1;

      // prefetch next tile's indices (hides index-load latency)
      const int tn = t + half;
      if (tn < NT) {
        const int e0 = tn * 128 + w * 32 + 2 * c, e1 = e0 + 1;
        if (SORTED) {
          ps0 = src_s[e0]; ps1 = src_s[e1];
          pd0 = dst_s[e0]; pd1 = dst_s[e1];
          pdd0 = bf2f(dist_s[e0]); pdd1 = bf2f(dist_s[e1]);
        } else {
          ps0 = eidx[e0]; ps1 = eidx[e1];
          pd0 = eidx[E_CNT + e0]; pd1 = eidx[E_CNT + e1];
          pdd0 = edist[e0]; pdd1 = edist[e1];
        }
      }

      f32x4 acc[2][8];
#pragma unroll
      for (int mt = 0; mt < 2; ++mt)
#pragma unroll
        for (int nt = 0; nt < 8; ++nt) acc[mt][nt] = vzero;

#pragma unroll
      for (int kt = 0; kt < 5; ++kt) {
        bf16x8 a0, a1;
        if (kt < 4) {
          const size_t r0 = (size_t)((kt < 2) ? s0 : d0) * 64 + (kt & 1) * 32 + g * 8;
          const size_t r1 = (size_t)((kt < 2) ? s1 : d1) * 64 + (kt & 1) * 32 + g * 8;
          if (SORTED) {
            a0 = *(const bf16x8*)&hb[r0];
            a1 = *(const bf16x8*)&hb[r1];
          } else {
            const f32x4 pa = *(const f32x4*)(h + r0), pb = *(const f32x4*)(h + r0 + 4);
            const f32x4 qa = *(const f32x4*)(h + r1), qb = *(const f32x4*)(h + r1 + 4);
            u32x4 u0 = {pack2(pa[0], pa[1]), pack2(pa[2], pa[3]),
                        pack2(pb[0], pb[1]), pack2(pb[2], pb[3])};
            u32x4 u1 = {pack2(qa[0], qa[1]), pack2(qa[2], qa[3]),
                        pack2(qb[0], qb[1]), pack2(qb[2], qb[3])};
            a0 = __builtin_bit_cast(bf16x8, u0);
            a1 = __builtin_bit_cast(bf16x8, u1);
          }
        } else {
          float t0[8], t1[8];
#pragma unroll
          for (int j = 0; j < 8; ++j) {
            t0[j] = silu_f(fmaf(dd0, we1s[j], be1s[j]));
            t1[j] = silu_f(fmaf(dd1, we1s[j], be1s[j]));
          }
          u32x4 u0 = {cvtpk(t0[0], t0[1]), cvtpk(t0[2], t0[3]),
                      cvtpk(t0[4], t0[5]), cvtpk(t0[6], t0[7])};
          u32x4 u1 = {cvtpk(t1[0], t1[1]), cvtpk(t1[2], t1[3]),
                      cvtpk(t1[4], t1[5]), cvtpk(t1[6], t1[7])};
          a0 = __builtin_bit_cast(bf16x8, u0);
          a1 = __builtin_bit_cast(bf16x8, u1);
        }
#pragma unroll
        for (int nt = 0; nt < 8; ++nt) {
          const bf16x8 b = *(const bf16x8*)&wft[(((kt << 3) + nt) << 9) + (l << 3)];
          acc[0][nt] = __builtin_amdgcn_mfma_f32_16x16x32_bf16(a0, b, acc[0][nt], 0, 0, 0);
          acc[1][nt] = __builtin_amdgcn_mfma_f32_16x16x32_bf16(a1, b, acc[1][nt], 0, 0, 0);
        }
      }

      f32x4 acc2[2][4];
#pragma unroll
      for (int nt = 0; nt < 4; ++nt) { acc2[0][nt] = vzero; acc2[1][nt] = vzero; }

#pragma unroll
      for (int mt = 0; mt < 2; ++mt) {
        // silu + HW-packed bf16 -> one ds_write_b128 per output row
#pragma unroll
        for (int r = 0; r < 4; ++r) {
          const float v0 = silu_f(acc[mt][0][r] + bias1[0]);
          const float v1 = silu_f(acc[mt][1][r] + bias1[1]);
          const float v2 = silu_f(acc[mt][2][r] + bias1[2]);
          const float v3 = silu_f(acc[mt][3][r] + bias1[3]);
          const float v4 = silu_f(acc[mt][4][r] + bias1[4]);
          const float v5 = silu_f(acc[mt][5][r] + bias1[5]);
          const float v6 = silu_f(acc[mt][6][r] + bias1[6]);
          const float v7 = silu_f(acc[mt][7][r] + bias1[7]);
          u32x4 pkv = {cvtpk(v0, v1), cvtpk(v2, v3), cvtpk(v4, v5), cvtpk(v6, v7)};
          *(u32x4*)&myscr[(4 * g + r) * 136 + c * 8] = pkv;
        }
#pragma unroll
        for (int kt2 = 0; kt2 < 4; ++kt2) {
          const bf16x8 a2 = *(const bf16x8*)&myscr[c * 136 + kt2 * 32 + g * 8];
#pragma unroll
          for (int nt2 = 0; nt2 < 4; ++nt2) {
            const bf16x8 b2 = *(const bf16x8*)&w2t[(((kt2 << 2) + nt2) << 9) + (l << 3)];
            acc2[mt][nt2] = __builtin_amdgcn_mfma_f32_16x16x32_bf16(a2, b2, acc2[mt][nt2], 0, 0, 0);
          }
        }
      }

      // RLE over 8 consecutive (sorted) edges base+8g..+7
      int des[8];
#pragma unroll
      for (int s = 0; s < 8; ++s)
        des[s] = __shfl((s & 1) ? d1 : d0, 4 * g + (s >> 1));

      float run[4];
      int cur = des[0];
#pragma unroll
      for (int nt2 = 0; nt2 < 4; ++nt2) run[nt2] = acc2[0][nt2][0] + bias2[nt2];
#pragma unroll
      for (int s = 1; s < 8; ++s) {
        const int mt = s & 1, r = s >> 1;
        if (des[s] == cur) {
#pragma unroll
          for (int nt2 = 0; nt2 < 4; ++nt2) run[nt2] += acc2[mt][nt2][r] + bias2[nt2];
        } else {
#pragma unroll
          for (int nt2 = 0; nt2 < 4; ++nt2)
            unsafeAtomicAdd(&out[(size_t)cur * 64 + nt2 * 16 + c], run[nt2]);
          cur = des[s];
#pragma unroll
          for (int nt2 = 0; nt2 < 4; ++nt2) run[nt2] = acc2[mt][nt2][r] + bias2[nt2];
        }
      }
#pragma unroll
      for (int nt2 = 0; nt2 < 4; ++nt2)
        unsafeAtomicAdd(&out[(size_t)cur * 64 + nt2 * 16 + c], run[nt2]);
    }
  } else {
    // ================= coord path (r9 k_coord, stride=half) =================
    float we1s[8], be1s[8];
#pragma unroll
    for (int j = 0; j < 8; ++j) { we1s[j] = We1[g * 8 + j]; be1s[j] = be1[g * 8 + j]; }
    float b1c[8], wc2l[8];  // permuted: lane owns true features c*8..c*8+7
#pragma unroll
    for (int nt = 0; nt < 8; ++nt) {
      b1c[nt] = biasc[c * 8 + nt];
      wc2l[nt] = Wc2[c * 8 + nt];
    }

    int t = (int)blockIdx.x - half;
    int ps0 = 0, ps1 = 0, pd0 = 0, pd1 = 0;
    float pdd0 = 0.f, pdd1 = 0.f;
    if (t < NT) {
      const int e0 = t * 128 + w * 32 + 2 * c, e1 = e0 + 1;
      if (SORTED) {
        ps0 = src_s[e0]; ps1 = src_s[e1];
        pd0 = dst_s[e0]; pd1 = dst_s[e1];
        pdd0 = bf2f(dist_s[e0]); pdd1 = bf2f(dist_s[e1]);
      } else {
        ps0 = eidx[e0]; ps1 = eidx[e1];
        pd0 = eidx[E_CNT + e0]; pd1 = eidx[E_CNT + e1];
        pdd0 = edist[e0]; pdd1 = edist[e1];
      }
    }

    for (; t < NT; t += half) {
      const short* wft = Wfc;
      asm volatile("" : "+v"(wft));

      const int s0 = ps0, s1 = ps1, d0 = pd0, d1 = pd1;
      const float dd0 = pdd0, dd1 = pdd1;

      const int tn = t + half;
      if (tn < NT) {
        const int e0 = tn * 128 + w * 32 + 2 * c, e1 = e0 + 1;
        if (SORTED) {
          ps0 = src_s[e0]; ps1 = src_s[e1];
          pd0 = dst_s[e0]; pd1 = dst_s[e1];
          pdd0 = bf2f(dist_s[e0]); pdd1 = bf2f(dist_s[e1]);
        } else {
          ps0 = eidx[e0]; ps1 = eidx[e1];
          pd0 = eidx[E_CNT + e0]; pd1 = eidx[E_CNT + e1];
          pdd0 = edist[e0]; pdd1 = edist[e1];
        }
      }

      f32x4 acc[2][8];
#pragma unroll
      for (int mt = 0; mt < 2; ++mt)
#pragma unroll
        for (int nt = 0; nt < 8; ++nt) acc[mt][nt] = vzero;

#pragma unroll
      for (int kt = 0; kt < 5; ++kt) {
        bf16x8 a0, a1;
        if (kt < 4) {
          const size_t r0 = (size_t)((kt < 2) ? s0 : d0) * 64 + (kt & 1) * 32 + g * 8;
          const size_t r1 = (size_t)((kt < 2) ? s1 : d1) * 64 + (kt & 1) * 32 + g * 8;
          if (SORTED) {
            a0 = *(const bf16x8*)&hb[r0];
            a1 = *(const bf16x8*)&hb[r1];
          } else {
            const f32x4 pa = *(const f32x4*)(h + r0), pb = *(const f32x4*)(h + r0 + 4);
            const f32x4 qa = *(const f32x4*)(h + r1), qb = *(const f32x4*)(h + r1 + 4);
            u32x4 u0 = {pack2(pa[0], pa[1]), pack2(pa[2], pa[3]),
                        pack2(pb[0], pb[1]), pack2(pb[2], pb[3])};
            u32x4 u1 = {pack2(qa[0], qa[1]), pack2(qa[2], qa[3]),
                        pack2(qb[0], qb[1]), pack2(qb[2], qb[3])};
            a0 = __builtin_bit_cast(bf16x8, u0);
            a1 = __builtin_bit_cast(bf16x8, u1);
          }
        } else {
          float t0[8], t1[8];
#pragma unroll
          for (int j = 0; j < 8; ++j) {
            t0[j] = silu_f(fmaf(dd0, we1s[j], be1s[j]));
            t1[j] = silu_f(fmaf(dd1, we1s[j], be1s[j]));
          }
          u32x4 u0 = {cvtpk(t0[0], t0[1]), cvtpk(t0[2], t0[3]),
                      cvtpk(t0[4], t0[5]), cvtpk(t0[6], t0[7])};
          u32x4 u1 = {cvtpk(t1[0], t1[1]), cvtpk(t1[2], t1[3]),
                      cvtpk(t1[4], t1[5]), cvtpk(t1[6], t1[7])};
          a0 = __builtin_bit_cast(bf16x8, u0);
          a1 = __builtin_bit_cast(bf16x8, u1);
        }
#pragma unroll
        for (int nt = 0; nt < 8; ++nt) {
          const bf16x8 b = *(const bf16x8*)&wft[(((kt << 3) + nt) << 9) + (l << 3)];
          acc[0][nt] = __builtin_amdgcn_mfma_f32_16x16x32_bf16(a0, b, acc[0][nt], 0, 0, 0);
          acc[1][nt] = __builtin_amdgcn_mfma_f32_16x16x32_bf16(a1, b, acc[1][nt], 0, 0, 0);
        }
      }

      // coord_w partials + 16-lane butterfly (all lanes end with all 8 values)
      float p0[4], p1[4];
#pragma unroll
      for (int r = 0; r < 4; ++r) {
        float a = 0.f, bsum = 0.f;
#pragma unroll
        for (int nt = 0; nt < 8; ++nt) {
          a += silu_f(acc[0][nt][r] + b1c[nt]) * wc2l[nt];
          bsum += silu_f(acc[1][nt][r] + b1c[nt]) * wc2l[nt];
        }
        p0[r] = a; p1[r] = bsum;
      }
#pragma unroll
      for (int m = 1; m < 16; m <<= 1)
#pragma unroll
        for (int r = 0; r < 4; ++r) {
          p0[r] += __shfl_xor(p0[r], m);
          p1[r] += __shfl_xor(p1[r], m);
        }

      // lane c<8 of each group handles edge base+8g+c (consecutive when sorted)
      const int mt = c & 1, rr = c >> 1;
      const int dA = __shfl(d0, 4 * g + rr), dB = __shfl(d1, 4 * g + rr);
      const int sA = __shfl(s0, 4 * g + rr), sB = __shfl(s1, 4 * g + rr);
      const int dstE = mt ? dB : dA;
      const int srcE = mt ? sB : sA;
      if (c < 8) {
        const float cwp0 = (rr == 0) ? p0[0] : (rr == 1) ? p0[1] : (rr == 2) ? p0[2] : p0[3];
        const float cwp1 = (rr == 0) ? p1[0] : (rr == 1) ? p1[1] : (rr == 2) ? p1[2] : p1[3];
        const float cw = mt ? cwp1 : cwp0;
        const float ax = x[srcE * 3 + 0] - x[dstE * 3 + 0];
        const float ay = x[srcE * 3 + 1] - x[dstE * 3 + 1];
        const float az = x[srcE * 3 + 2] - x[dstE * 3 + 2];
        float len = sqrtf(fmaf(ax, ax, fmaf(ay, ay, az * az)));
        len = fmaxf(len, 1e-8f);
        const float scl = cw / len;
        float vx = scl * ax, vy = scl * ay, vz = scl * az;
        // segmented inclusive scan over the 8 lanes (equal-dst runs, sorted)
#pragma unroll
        for (int k = 1; k < 8; k <<= 1) {
          const float tx = __shfl(vx, l - k);
          const float ty = __shfl(vy, l - k);
          const float tz = __shfl(vz, l - k);
          const int td = __shfl(dstE, l - k);
          if (c >= k && td == dstE) { vx += tx; vy += ty; vz += tz; }
        }
        const int dnx = __shfl(dstE, l + 1);
        if (c == 7 || dnx != dstE) {
          unsafeAtomicAdd(&xo[dstE * 3 + 0], vx);
          unsafeAtomicAdd(&xo[dstE * 3 + 1], vy);
          unsafeAtomicAdd(&xo[dstE * 3 + 2], vz);
        }
      }
    }
  }
}

extern "C" void kernel_launch(void* const* d_in, const int* in_sizes, int n_in,
                              void* d_out, int out_size, void* d_ws, size_t ws_size,
                              hipStream_t stream) {
  const float* h = (const float*)d_in[0];
  const float* x = (const float*)d_in[1];
  const float* edist = (const float*)d_in[2];
  const float* We1 = (const float*)d_in[3];
  const float* be1 = (const float*)d_in[4];
  const float* We2 = (const float*)d_in[5];
  const float* be2 = (const float*)d_in[6];
  const float* Wn1 = (const float*)d_in[7];
  const float* bn1 = (const float*)d_in[8];
  const float* Wn2 = (const float*)d_in[9];
  const float* bn2 = (const float*)d_in[10];
  const float* Wc1 = (const float*)d_in[11];
  const float* bc1 = (const float*)d_in[12];
  const float* Wc2 = (const float*)d_in[13];
  const int* eidx = (const int*)d_in[14];
  float* out = (float*)d_out;
  float* xo = out + 3200000;

  char* wsb = (char*)d_ws;
  int* cursor = (int*)(wsb + OFF_CURSOR);
  short* Wfn = (short*)(wsb + OFF_WFN);
  short* Wfc = (short*)(wsb + OFF_WFC);
  short* W2f = (short*)(wsb + OFF_W2F);
  float* biasn = (float*)(wsb + OFF_BIASN);
  float* biasc = (float*)(wsb + OFF_BIASC);
  int* src_s = (int*)(wsb + OFF_SRC);
  int* dst_s = (int*)(wsb + OFF_DST);
  short* dist_s = (short*)(wsb + OFF_DIST);
  short* hb = (short*)(wsb + OFF_HB);

  const bool full = (ws_size >= (size_t)REQ_FULL);

  if (full) {
    hipMemsetAsync(cursor, 0, N_CNT * sizeof(int), stream);
    k_pre<true><<<dim3(6422), dim3(256), 0, stream>>>(h, x, out, hb, eidx, cursor,
                                                      Wn1, Wc1, We2, bn1, bc1, be2, Wn2,
                                                      Wfn, Wfc, W2f, biasn, biasc);
    k_scan<<<dim3(1), dim3(1024), 0, stream>>>(cursor);
    k_fill<<<dim3(3125), dim3(256), 0, stream>>>(eidx, edist, cursor, src_s, dst_s, dist_s);
    k_main<true><<<dim3(512), dim3(256), 0, stream>>>(
        h, hb, x, edist, We1, be1, bn2, Wc2, eidx, src_s, dst_s, dist_s,
        Wfn, Wfc, W2f, biasn, biasc, out, xo);
  } else {
    k_pre<false><<<dim3(3297), dim3(256), 0, stream>>>(h, x, out, nullptr, eidx, nullptr,
                                                       Wn1, Wc1, We2, bn1, bc1, be2, Wn2,
                                                       Wfn, Wfc, W2f, biasn, biasc);
    k_main<false><<<dim3(512), dim3(256), 0, stream>>>(
        h, nullptr, x, edist, We1, be1, bn2, Wc2, eidx, nullptr, nullptr, nullptr,
        Wfn, Wfc, W2f, biasn, biasc, out, xo);
  }
}

// Round 12
// 411.172 us; speedup vs baseline: 1.7298x; 1.1975x over previous
//
#include <hip/hip_runtime.h>
#include <cstdint>
#include <cstddef>

#define E_CNT 800000
#define N_CNT 50000
#define NT 6250  // tiles of 128 edges (4 waves x 32)

typedef short bf16x8 __attribute__((ext_vector_type(8)));
typedef short s16x4 __attribute__((ext_vector_type(4)));
typedef float f32x4 __attribute__((ext_vector_type(4)));
typedef uint32_t u32x4 __attribute__((ext_vector_type(4)));

// ws byte offsets (identical to round-9/11 known-good layout)
#define OFF_CURSOR 0
#define OFF_WFN 200064
#define OFF_WFC 241024
#define OFF_W2F 281984
#define OFF_BIASN 298368
#define OFF_BIASC 298880
#define OFF_SRC 299520
#define OFF_DST 3499520
#define OFF_DIST 6699520
#define OFF_HB 8299520
#define REQ_FULL 14699520

__device__ __forceinline__ short f2bf(float v) {
  uint32_t u = __builtin_bit_cast(uint32_t, v);
  u = (u + 0x7FFFu + ((u >> 16) & 1u)) >> 16;
  return (short)u;
}
__device__ __forceinline__ float bf2f(short s) {
  uint32_t u = ((uint32_t)(uint16_t)s) << 16;
  return __builtin_bit_cast(float, u);
}
__device__ __forceinline__ uint32_t pack2(float lo, float hi) {
  return ((uint32_t)(uint16_t)f2bf(hi) << 16) | (uint32_t)(uint16_t)f2bf(lo);
}
// HW packed f32->bf16 (RNE), 1 instr per 2 values (no builtin on gfx950)
__device__ __forceinline__ uint32_t cvtpk(float lo, float hi) {
  uint32_t r;
  asm("v_cvt_pk_bf16_f32 %0, %1, %2" : "=v"(r) : "v"(lo), "v"(hi));
  return r;
}
__device__ __forceinline__ float silu_f(float v) {
  return v * (1.0f / (1.0f + __expf(-v)));
}

// ---- prep: init (copy + bf16 h) | fragment-linear weights | histogram ----
// GEMM1 frags FEATURE-PERMUTED: frag col (nt, lane c) = true feature c*8+nt.
template <bool FULL>
__global__ void k_pre(const float* __restrict__ h, const float* __restrict__ x,
                      float* __restrict__ out, short* __restrict__ hb,
                      const int* __restrict__ eidx, int* __restrict__ cursor,
                      const float* __restrict__ W1n, const float* __restrict__ W1c,
                      const float* __restrict__ We2, const float* __restrict__ bn1,
                      const float* __restrict__ bc1, const float* __restrict__ be2,
                      const float* __restrict__ Wn2,
                      short* __restrict__ Wfn, short* __restrict__ Wfc,
                      short* __restrict__ W2f, float* __restrict__ biasn,
                      float* __restrict__ biasc) {
  const int b = (int)blockIdx.x;
  if (b < 3272) {
    const int i = b * 256 + (int)threadIdx.x;
    if (i < 800000) {
      const f32x4 v = ((const f32x4*)h)[i];
      ((f32x4*)out)[i] = v;
      if (FULL) {
        s16x4 p;
#pragma unroll
        for (int j = 0; j < 4; ++j) p[j] = f2bf(v[j]);
        *(s16x4*)(hb + i * 4) = p;
      }
    } else if (i < 837500) {
      ((f32x4*)out)[i] = ((const f32x4*)x)[i - 800000];
    }
  } else if (b < 3297) {
    const int idx = (b - 3272) * 4 + ((int)threadIdx.x >> 6);
    const int l = (int)threadIdx.x & 63;
    if (idx < 80) {
      const int fid = (idx < 40) ? idx : (idx - 40);
      const float* W1 = (idx < 40) ? W1n : W1c;
      short* Wf = (idx < 40) ? Wfn : Wfc;
      const int kt = fid >> 3, nt = fid & 7;
      const int feat = (l & 15) * 8 + nt;  // permuted feature mapping
      const int k0 = kt * 32 + (l >> 4) * 8;
      bf16x8 v;
#pragma unroll
      for (int j = 0; j < 8; ++j) {
        const int k = k0 + j;
        float val;
        if (k < 128) {
          val = W1[k * 128 + feat];
        } else {
          float s = 0.f;
          for (int cc = 0; cc < 32; ++cc)
            s = fmaf(We2[(k - 128) * 32 + cc], W1[(128 + cc) * 128 + feat], s);
          val = s;
        }
        v[j] = f2bf(val);
      }
      *(bf16x8*)&Wf[(fid * 64 + l) * 8] = v;
    } else if (idx < 96) {
      const int fid = idx - 80;
      const int kt2 = fid >> 2, nt2 = fid & 3;
      bf16x8 v;
#pragma unroll
      for (int j = 0; j < 8; ++j)
        v[j] = f2bf(Wn2[(kt2 * 32 + (l >> 4) * 8 + j) * 64 + nt2 * 16 + (l & 15)]);
      *(bf16x8*)&W2f[(fid * 64 + l) * 8] = v;
    } else if (idx == 96) {
      for (int col = l; col < 128; col += 64) {
        float sn = bn1[col], sc = bc1[col];
        for (int cc = 0; cc < 32; ++cc) {
          sn = fmaf(be2[cc], W1n[(128 + cc) * 128 + col], sn);
          sc = fmaf(be2[cc], W1c[(128 + cc) * 128 + col], sc);
        }
        biasn[col] = sn;
        biasc[col] = sc;
      }
    }
  } else if (FULL) {
    const int e = (b - 3297) * 256 + (int)threadIdx.x;
    if (e < E_CNT) atomicAdd(&cursor[eidx[E_CNT + e]], 1);
  }
}

__global__ __launch_bounds__(1024) void k_scan(int* __restrict__ cursor) {
  __shared__ int part[1024];
  const int t = (int)threadIdx.x;
  const int b0 = t * 49;
  int n = N_CNT - b0;
  n = n < 0 ? 0 : (n > 49 ? 49 : n);
  int s = 0;
  for (int i = 0; i < n; ++i) s += cursor[b0 + i];
  part[t] = s;
  __syncthreads();
  for (int off = 1; off < 1024; off <<= 1) {
    const int u = (t >= off) ? part[t - off] : 0;
    __syncthreads();
    part[t] += u;
    __syncthreads();
  }
  int run = (t == 0) ? 0 : part[t - 1];
  for (int i = 0; i < n; ++i) {
    const int old = cursor[b0 + i];
    cursor[b0 + i] = run;
    run += old;
  }
}

__global__ void k_fill(const int* __restrict__ eidx, const float* __restrict__ edist,
                       int* __restrict__ cursor, int* __restrict__ src_s,
                       int* __restrict__ dst_s, short* __restrict__ dist_s) {
  const int e = (int)(blockIdx.x * 256 + threadIdx.x);
  if (e < E_CNT) {
    const int d = eidx[E_CNT + e];
    const int pos = atomicAdd(&cursor[d], 1);
    src_s[pos] = eidx[e];
    dst_s[pos] = d;
    dist_s[pos] = f2bf(edist[e]);
  }
}

// ---- fused main: blocks [0,half) = node path, [half,2*half) = coord path.
// SORTED path software-pipelines the A-operand gathers: A-frags for tile t+1
// are issued right after GEMM1 consumes tile t's frags, so the epilogue hides
// the L2 gather latency. Indices stay one tile further ahead.
template <bool SORTED>
__global__ __launch_bounds__(256, 2) void k_main(
    const float* __restrict__ h, const short* __restrict__ hb,
    const float* __restrict__ x, const float* __restrict__ edist,
    const float* __restrict__ We1, const float* __restrict__ be1,
    const float* __restrict__ bn2, const float* __restrict__ Wc2,
    const int* __restrict__ eidx,
    const int* __restrict__ src_s, const int* __restrict__ dst_s,
    const short* __restrict__ dist_s,
    const short* __restrict__ Wfn, const short* __restrict__ Wfc,
    const short* __restrict__ W2f,
    const float* __restrict__ biasn, const float* __restrict__ biasc,
    float* __restrict__ out, float* __restrict__ xo) {
  __shared__ __align__(16) short scr[4][16 * 136];

  const int tid = (int)threadIdx.x;
  const int w = tid >> 6, l = tid & 63, g = l >> 4, c = l & 15;
  const f32x4 vzero = {0.f, 0.f, 0.f, 0.f};
  const int half = (int)(gridDim.x >> 1);

  if ((int)blockIdx.x < half) {
    // ================= node path =================
    short* myscr = &scr[w][0];

    float we1s[8], be1s[8];
#pragma unroll
    for (int j = 0; j < 8; ++j) { we1s[j] = We1[g * 8 + j]; be1s[j] = be1[g * 8 + j]; }
    float bias1[8];  // permuted: lane owns true features c*8..c*8+7
#pragma unroll
    for (int nt = 0; nt < 8; ++nt) bias1[nt] = biasn[c * 8 + nt];
    float bias2[4];
#pragma unroll
    for (int nt = 0; nt < 4; ++nt) bias2[nt] = bn2[nt * 16 + c];

    int t = (int)blockIdx.x;
    // current-tile indices, next-tile indices, prefetched A-frags (tile t)
    int cs0 = 0, cs1 = 0, cd0 = 0, cd1 = 0;
    float cdd0 = 0.f, cdd1 = 0.f;
    int ns0 = 0, ns1 = 0, nd0 = 0, nd1 = 0;
    float ndd0 = 0.f, ndd1 = 0.f;
    bf16x8 af0[4], af1[4];
    {
      const int e0 = t * 128 + w * 32 + 2 * c;
      if (SORTED) {
        cs0 = src_s[e0]; cs1 = src_s[e0 + 1];
        cd0 = dst_s[e0]; cd1 = dst_s[e0 + 1];
        cdd0 = bf2f(dist_s[e0]); cdd1 = bf2f(dist_s[e0 + 1]);
#pragma unroll
        for (int kt = 0; kt < 4; ++kt) {
          af0[kt] = *(const bf16x8*)&hb[(size_t)((kt < 2) ? cs0 : cd0) * 64 + (kt & 1) * 32 + g * 8];
          af1[kt] = *(const bf16x8*)&hb[(size_t)((kt < 2) ? cs1 : cd1) * 64 + (kt & 1) * 32 + g * 8];
        }
        const int tn = t + half;
        if (tn < NT) {
          const int e1 = tn * 128 + w * 32 + 2 * c;
          ns0 = src_s[e1]; ns1 = src_s[e1 + 1];
          nd0 = dst_s[e1]; nd1 = dst_s[e1 + 1];
          ndd0 = bf2f(dist_s[e1]); ndd1 = bf2f(dist_s[e1 + 1]);
        }
      } else {
        cs0 = eidx[e0]; cs1 = eidx[e0 + 1];
        cd0 = eidx[E_CNT + e0]; cd1 = eidx[E_CNT + e0 + 1];
        cdd0 = edist[e0]; cdd1 = edist[e0 + 1];
      }
    }

    for (; t < NT; t += half) {
      const short* wft = Wfn;
      const short* w2t = W2f;
      asm volatile("" : "+v"(wft), "+v"(w2t));

      const int s0 = cs0, s1 = cs1, d0 = cd0, d1 = cd1;
      const float dd0 = cdd0, dd1 = cdd1;

      // edge-MLP frags for the current tile
      bf16x8 ae0, ae1;
      {
        float t0[8], t1[8];
#pragma unroll
        for (int j = 0; j < 8; ++j) {
          t0[j] = silu_f(fmaf(dd0, we1s[j], be1s[j]));
          t1[j] = silu_f(fmaf(dd1, we1s[j], be1s[j]));
        }
        u32x4 u0 = {cvtpk(t0[0], t0[1]), cvtpk(t0[2], t0[3]),
                    cvtpk(t0[4], t0[5]), cvtpk(t0[6], t0[7])};
        u32x4 u1 = {cvtpk(t1[0], t1[1]), cvtpk(t1[2], t1[3]),
                    cvtpk(t1[4], t1[5]), cvtpk(t1[6], t1[7])};
        ae0 = __builtin_bit_cast(bf16x8, u0);
        ae1 = __builtin_bit_cast(bf16x8, u1);
      }

      f32x4 acc[2][8];
#pragma unroll
      for (int mt = 0; mt < 2; ++mt)
#pragma unroll
        for (int nt = 0; nt < 8; ++nt) acc[mt][nt] = vzero;

#pragma unroll
      for (int kt = 0; kt < 5; ++kt) {
        bf16x8 a0, a1;
        if (kt < 4) {
          if (SORTED) {
            a0 = af0[kt];
            a1 = af1[kt];
          } else {
            const size_t r0 = (size_t)((kt < 2) ? s0 : d0) * 64 + (kt & 1) * 32 + g * 8;
            const size_t r1 = (size_t)((kt < 2) ? s1 : d1) * 64 + (kt & 1) * 32 + g * 8;
            const f32x4 pa = *(const f32x4*)(h + r0), pb = *(const f32x4*)(h + r0 + 4);
            const f32x4 qa = *(const f32x4*)(h + r1), qb = *(const f32x4*)(h + r1 + 4);
            u32x4 u0 = {pack2(pa[0], pa[1]), pack2(pa[2], pa[3]),
                        pack2(pb[0], pb[1]), pack2(pb[2], pb[3])};
            u32x4 u1 = {pack2(qa[0], qa[1]), pack2(qa[2], qa[3]),
                        pack2(qb[0], qb[1]), pack2(qb[2], qb[3])};
            a0 = __builtin_bit_cast(bf16x8, u0);
            a1 = __builtin_bit_cast(bf16x8, u1);
          }
        } else {
          a0 = ae0;
          a1 = ae1;
        }
#pragma unroll
        for (int nt = 0; nt < 8; ++nt) {
          const bf16x8 b = *(const bf16x8*)&wft[(((kt << 3) + nt) << 9) + (l << 3)];
          acc[0][nt] = __builtin_amdgcn_mfma_f32_16x16x32_bf16(a0, b, acc[0][nt], 0, 0, 0);
          acc[1][nt] = __builtin_amdgcn_mfma_f32_16x16x32_bf16(a1, b, acc[1][nt], 0, 0, 0);
        }
      }

      // issue next tile's A-gathers NOW; epilogue hides their latency
      if (SORTED && (t + half) < NT) {
#pragma unroll
        for (int kt = 0; kt < 4; ++kt) {
          af0[kt] = *(const bf16x8*)&hb[(size_t)((kt < 2) ? ns0 : nd0) * 64 + (kt & 1) * 32 + g * 8];
          af1[kt] = *(const bf16x8*)&hb[(size_t)((kt < 2) ? ns1 : nd1) * 64 + (kt & 1) * 32 + g * 8];
        }
      }

      f32x4 acc2[2][4];
#pragma unroll
      for (int nt = 0; nt < 4; ++nt) { acc2[0][nt] = vzero; acc2[1][nt] = vzero; }

#pragma unroll
      for (int mt = 0; mt < 2; ++mt) {
        // silu + HW-packed bf16 -> one ds_write_b128 per output row
#pragma unroll
        for (int r = 0; r < 4; ++r) {
          const float v0 = silu_f(acc[mt][0][r] + bias1[0]);
          const float v1 = silu_f(acc[mt][1][r] + bias1[1]);
          const float v2 = silu_f(acc[mt][2][r] + bias1[2]);
          const float v3 = silu_f(acc[mt][3][r] + bias1[3]);
          const float v4 = silu_f(acc[mt][4][r] + bias1[4]);
          const float v5 = silu_f(acc[mt][5][r] + bias1[5]);
          const float v6 = silu_f(acc[mt][6][r] + bias1[6]);
          const float v7 = silu_f(acc[mt][7][r] + bias1[7]);
          u32x4 pkv = {cvtpk(v0, v1), cvtpk(v2, v3), cvtpk(v4, v5), cvtpk(v6, v7)};
          *(u32x4*)&myscr[(4 * g + r) * 136 + c * 8] = pkv;
        }
#pragma unroll
        for (int kt2 = 0; kt2 < 4; ++kt2) {
          const bf16x8 a2 = *(const bf16x8*)&myscr[c * 136 + kt2 * 32 + g * 8];
#pragma unroll
          for (int nt2 = 0; nt2 < 4; ++nt2) {
            const bf16x8 b2 = *(const bf16x8*)&w2t[(((kt2 << 2) + nt2) << 9) + (l << 3)];
            acc2[mt][nt2] = __builtin_amdgcn_mfma_f32_16x16x32_bf16(a2, b2, acc2[mt][nt2], 0, 0, 0);
          }
        }
      }

      // RLE over 8 consecutive (sorted) edges base+8g..+7
      int des[8];
#pragma unroll
      for (int s = 0; s < 8; ++s)
        des[s] = __shfl((s & 1) ? d1 : d0, 4 * g + (s >> 1));

      float run[4];
      int cur = des[0];
#pragma unroll
      for (int nt2 = 0; nt2 < 4; ++nt2) run[nt2] = acc2[0][nt2][0] + bias2[nt2];
#pragma unroll
      for (int s = 1; s < 8; ++s) {
        const int mt = s & 1, r = s >> 1;
        if (des[s] == cur) {
#pragma unroll
          for (int nt2 = 0; nt2 < 4; ++nt2) run[nt2] += acc2[mt][nt2][r] + bias2[nt2];
        } else {
#pragma unroll
          for (int nt2 = 0; nt2 < 4; ++nt2)
            unsafeAtomicAdd(&out[(size_t)cur * 64 + nt2 * 16 + c], run[nt2]);
          cur = des[s];
#pragma unroll
          for (int nt2 = 0; nt2 < 4; ++nt2) run[nt2] = acc2[mt][nt2][r] + bias2[nt2];
        }
      }
#pragma unroll
      for (int nt2 = 0; nt2 < 4; ++nt2)
        unsafeAtomicAdd(&out[(size_t)cur * 64 + nt2 * 16 + c], run[nt2]);

      // rotate indices and load tile t+2*half's indices
      cs0 = ns0; cs1 = ns1; cd0 = nd0; cd1 = nd1; cdd0 = ndd0; cdd1 = ndd1;
      const int t2 = t + 2 * half;
      if (t2 < NT) {
        const int e2 = t2 * 128 + w * 32 + 2 * c;
        if (SORTED) {
          ns0 = src_s[e2]; ns1 = src_s[e2 + 1];
          nd0 = dst_s[e2]; nd1 = dst_s[e2 + 1];
          ndd0 = bf2f(dist_s[e2]); ndd1 = bf2f(dist_s[e2 + 1]);
        } else {
          ns0 = eidx[e2]; ns1 = eidx[e2 + 1];
          nd0 = eidx[E_CNT + e2]; nd1 = eidx[E_CNT + e2 + 1];
          ndd0 = edist[e2]; ndd1 = edist[e2 + 1];
        }
      } else if (!SORTED) {
        // !SORTED path loads A inline from cur indices; keep them valid
      }
      if (!SORTED) {
        // for the unsorted fallback, "next" rotation degenerates: reload cur
        const int tn1 = t + half;
        if (tn1 < NT) {
          const int e1 = tn1 * 128 + w * 32 + 2 * c;
          cs0 = eidx[e1]; cs1 = eidx[e1 + 1];
          cd0 = eidx[E_CNT + e1]; cd1 = eidx[E_CNT + e1 + 1];
          cdd0 = edist[e1]; cdd1 = edist[e1 + 1];
        }
      }
    }
  } else {
    // ================= coord path =================
    float we1s[8], be1s[8];
#pragma unroll
    for (int j = 0; j < 8; ++j) { we1s[j] = We1[g * 8 + j]; be1s[j] = be1[g * 8 + j]; }
    float b1c[8], wc2l[8];  // permuted: lane owns true features c*8..c*8+7
#pragma unroll
    for (int nt = 0; nt < 8; ++nt) {
      b1c[nt] = biasc[c * 8 + nt];
      wc2l[nt] = Wc2[c * 8 + nt];
    }

    int t = (int)blockIdx.x - half;
    int cs0 = 0, cs1 = 0, cd0 = 0, cd1 = 0;
    float cdd0 = 0.f, cdd1 = 0.f;
    int ns0 = 0, ns1 = 0, nd0 = 0, nd1 = 0;
    float ndd0 = 0.f, ndd1 = 0.f;
    bf16x8 af0[4], af1[4];
    {
      const int e0 = t * 128 + w * 32 + 2 * c;
      if (SORTED) {
        cs0 = src_s[e0]; cs1 = src_s[e0 + 1];
        cd0 = dst_s[e0]; cd1 = dst_s[e0 + 1];
        cdd0 = bf2f(dist_s[e0]); cdd1 = bf2f(dist_s[e0 + 1]);
#pragma unroll
        for (int kt = 0; kt < 4; ++kt) {
          af0[kt] = *(const bf16x8*)&hb[(size_t)((kt < 2) ? cs0 : cd0) * 64 + (kt & 1) * 32 + g * 8];
          af1[kt] = *(const bf16x8*)&hb[(size_t)((kt < 2) ? cs1 : cd1) * 64 + (kt & 1) * 32 + g * 8];
        }
        const int tn = t + half;
        if (tn < NT) {
          const int e1 = tn * 128 + w * 32 + 2 * c;
          ns0 = src_s[e1]; ns1 = src_s[e1 + 1];
          nd0 = dst_s[e1]; nd1 = dst_s[e1 + 1];
          ndd0 = bf2f(dist_s[e1]); ndd1 = bf2f(dist_s[e1 + 1]);
        }
      } else {
        cs0 = eidx[e0]; cs1 = eidx[e0 + 1];
        cd0 = eidx[E_CNT + e0]; cd1 = eidx[E_CNT + e0 + 1];
        cdd0 = edist[e0]; cdd1 = edist[e0 + 1];
      }
    }

    for (; t < NT; t += half) {
      const short* wft = Wfc;
      asm volatile("" : "+v"(wft));

      const int s0 = cs0, s1 = cs1, d0 = cd0, d1 = cd1;
      const float dd0 = cdd0, dd1 = cdd1;

      bf16x8 ae0, ae1;
      {
        float t0[8], t1[8];
#pragma unroll
        for (int j = 0; j < 8; ++j) {
          t0[j] = silu_f(fmaf(dd0, we1s[j], be1s[j]));
          t1[j] = silu_f(fmaf(dd1, we1s[j], be1s[j]));
        }
        u32x4 u0 = {cvtpk(t0[0], t0[1]), cvtpk(t0[2], t0[3]),
                    cvtpk(t0[4], t0[5]), cvtpk(t0[6], t0[7])};
        u32x4 u1 = {cvtpk(t1[0], t1[1]), cvtpk(t1[2], t1[3]),
                    cvtpk(t1[4], t1[5]), cvtpk(t1[6], t1[7])};
        ae0 = __builtin_bit_cast(bf16x8, u0);
        ae1 = __builtin_bit_cast(bf16x8, u1);
      }

      f32x4 acc[2][8];
#pragma unroll
      for (int mt = 0; mt < 2; ++mt)
#pragma unroll
        for (int nt = 0; nt < 8; ++nt) acc[mt][nt] = vzero;

#pragma unroll
      for (int kt = 0; kt < 5; ++kt) {
        bf16x8 a0, a1;
        if (kt < 4) {
          if (SORTED) {
            a0 = af0[kt];
            a1 = af1[kt];
          } else {
            const size_t r0 = (size_t)((kt < 2) ? s0 : d0) * 64 + (kt & 1) * 32 + g * 8;
            const size_t r1 = (size_t)((kt < 2) ? s1 : d1) * 64 + (kt & 1) * 32 + g * 8;
            const f32x4 pa = *(const f32x4*)(h + r0), pb = *(const f32x4*)(h + r0 + 4);
            const f32x4 qa = *(const f32x4*)(h + r1), qb = *(const f32x4*)(h + r1 + 4);
            u32x4 u0 = {pack2(pa[0], pa[1]), pack2(pa[2], pa[3]),
                        pack2(pb[0], pb[1]), pack2(pb[2], pb[3])};
            u32x4 u1 = {pack2(qa[0], qa[1]), pack2(qa[2], qa[3]),
                        pack2(qb[0], qb[1]), pack2(qb[2], qb[3])};
            a0 = __builtin_bit_cast(bf16x8, u0);
            a1 = __builtin_bit_cast(bf16x8, u1);
          }
        } else {
          a0 = ae0;
          a1 = ae1;
        }
#pragma unroll
        for (int nt = 0; nt < 8; ++nt) {
          const bf16x8 b = *(const bf16x8*)&wft[(((kt << 3) + nt) << 9) + (l << 3)];
          acc[0][nt] = __builtin_amdgcn_mfma_f32_16x16x32_bf16(a0, b, acc[0][nt], 0, 0, 0);
          acc[1][nt] = __builtin_amdgcn_mfma_f32_16x16x32_bf16(a1, b, acc[1][nt], 0, 0, 0);
        }
      }

      // issue next tile's A-gathers; the coord epilogue hides their latency
      if (SORTED && (t + half) < NT) {
#pragma unroll
        for (int kt = 0; kt < 4; ++kt) {
          af0[kt] = *(const bf16x8*)&hb[(size_t)((kt < 2) ? ns0 : nd0) * 64 + (kt & 1) * 32 + g * 8];
          af1[kt] = *(const bf16x8*)&hb[(size_t)((kt < 2) ? ns1 : nd1) * 64 + (kt & 1) * 32 + g * 8];
        }
      }

      // coord_w partials + 16-lane butterfly (all lanes end with all 8 values)
      float p0[4], p1[4];
#pragma unroll
      for (int r = 0; r < 4; ++r) {
        float a = 0.f, bsum = 0.f;
#pragma unroll
        for (int nt = 0; nt < 8; ++nt) {
          a += silu_f(acc[0][nt][r] + b1c[nt]) * wc2l[nt];
          bsum += silu_f(acc[1][nt][r] + b1c[nt]) * wc2l[nt];
        }
        p0[r] = a; p1[r] = bsum;
      }
#pragma unroll
      for (int m = 1; m < 16; m <<= 1)
#pragma unroll
        for (int r = 0; r < 4; ++r) {
          p0[r] += __shfl_xor(p0[r], m);
          p1[r] += __shfl_xor(p1[r], m);
        }

      // lane c<8 of each group handles edge base+8g+c (consecutive when sorted)
      const int mt = c & 1, rr = c >> 1;
      const int dA = __shfl(d0, 4 * g + rr), dB = __shfl(d1, 4 * g + rr);
      const int sA = __shfl(s0, 4 * g + rr), sB = __shfl(s1, 4 * g + rr);
      const int dstE = mt ? dB : dA;
      const int srcE = mt ? sB : sA;
      if (c < 8) {
        const float cwp0 = (rr == 0) ? p0[0] : (rr == 1) ? p0[1] : (rr == 2) ? p0[2] : p0[3];
        const float cwp1 = (rr == 0) ? p1[0] : (rr == 1) ? p1[1] : (rr == 2) ? p1[2] : p1[3];
        const float cw = mt ? cwp1 : cwp0;
        const float ax = x[srcE * 3 + 0] - x[dstE * 3 + 0];
        const float ay = x[srcE * 3 + 1] - x[dstE * 3 + 1];
        const float az = x[srcE * 3 + 2] - x[dstE * 3 + 2];
        float len = sqrtf(fmaf(ax, ax, fmaf(ay, ay, az * az)));
        len = fmaxf(len, 1e-8f);
        const float scl = cw / len;
        float vx = scl * ax, vy = scl * ay, vz = scl * az;
        // segmented inclusive scan over the 8 lanes (equal-dst runs, sorted)
#pragma unroll
        for (int k = 1; k < 8; k <<= 1) {
          const float tx = __shfl(vx, l - k);
          const float ty = __shfl(vy, l - k);
          const float tz = __shfl(vz, l - k);
          const int td = __shfl(dstE, l - k);
          if (c >= k && td == dstE) { vx += tx; vy += ty; vz += tz; }
        }
        const int dnx = __shfl(dstE, l + 1);
        if (c == 7 || dnx != dstE) {
          unsafeAtomicAdd(&xo[dstE * 3 + 0], vx);
          unsafeAtomicAdd(&xo[dstE * 3 + 1], vy);
          unsafeAtomicAdd(&xo[dstE * 3 + 2], vz);
        }
      }

      // rotate indices; load tile t+2*half's indices
      cs0 = ns0; cs1 = ns1; cd0 = nd0; cd1 = nd1; cdd0 = ndd0; cdd1 = ndd1;
      const int t2 = t + 2 * half;
      if (t2 < NT) {
        const int e2 = t2 * 128 + w * 32 + 2 * c;
        if (SORTED) {
          ns0 = src_s[e2]; ns1 = src_s[e2 + 1];
          nd0 = dst_s[e2]; nd1 = dst_s[e2 + 1];
          ndd0 = bf2f(dist_s[e2]); ndd1 = bf2f(dist_s[e2 + 1]);
        } else {
          ns0 = eidx[e2]; ns1 = eidx[e2 + 1];
          nd0 = eidx[E_CNT + e2]; nd1 = eidx[E_CNT + e2 + 1];
          ndd0 = edist[e2]; ndd1 = edist[e2 + 1];
        }
      }
      if (!SORTED) {
        const int tn1 = t + half;
        if (tn1 < NT) {
          const int e1 = tn1 * 128 + w * 32 + 2 * c;
          cs0 = eidx[e1]; cs1 = eidx[e1 + 1];
          cd0 = eidx[E_CNT + e1]; cd1 = eidx[E_CNT + e1 + 1];
          cdd0 = edist[e1]; cdd1 = edist[e1 + 1];
        }
      }
    }
  }
}

extern "C" void kernel_launch(void* const* d_in, const int* in_sizes, int n_in,
                              void* d_out, int out_size, void* d_ws, size_t ws_size,
                              hipStream_t stream) {
  const float* h = (const float*)d_in[0];
  const float* x = (const float*)d_in[1];
  const float* edist = (const float*)d_in[2];
  const float* We1 = (const float*)d_in[3];
  const float* be1 = (const float*)d_in[4];
  const float* We2 = (const float*)d_in[5];
  const float* be2 = (const float*)d_in[6];
  const float* Wn1 = (const float*)d_in[7];
  const float* bn1 = (const float*)d_in[8];
  const float* Wn2 = (const float*)d_in[9];
  const float* bn2 = (const float*)d_in[10];
  const float* Wc1 = (const float*)d_in[11];
  const float* bc1 = (const float*)d_in[12];
  const float* Wc2 = (const float*)d_in[13];
  const int* eidx = (const int*)d_in[14];
  float* out = (float*)d_out;
  float* xo = out + 3200000;

  char* wsb = (char*)d_ws;
  int* cursor = (int*)(wsb + OFF_CURSOR);
  short* Wfn = (short*)(wsb + OFF_WFN);
  short* Wfc = (short*)(wsb + OFF_WFC);
  short* W2f = (short*)(wsb + OFF_W2F);
  float* biasn = (float*)(wsb + OFF_BIASN);
  float* biasc = (float*)(wsb + OFF_BIASC);
  int* src_s = (int*)(wsb + OFF_SRC);
  int* dst_s = (int*)(wsb + OFF_DST);
  short* dist_s = (short*)(wsb + OFF_DIST);
  short* hb = (short*)(wsb + OFF_HB);

  const bool full = (ws_size >= (size_t)REQ_FULL);

  if (full) {
    hipMemsetAsync(cursor, 0, N_CNT * sizeof(int), stream);
    k_pre<true><<<dim3(6422), dim3(256), 0, stream>>>(h, x, out, hb, eidx, cursor,
                                                      Wn1, Wc1, We2, bn1, bc1, be2, Wn2,
                                                      Wfn, Wfc, W2f, biasn, biasc);
    k_scan<<<dim3(1), dim3(1024), 0, stream>>>(cursor);
    k_fill<<<dim3(3125), dim3(256), 0, stream>>>(eidx, edist, cursor, src_s, dst_s, dist_s);
    k_main<true><<<dim3(512), dim3(256), 0, stream>>>(
        h, hb, x, edist, We1, be1, bn2, Wc2, eidx, src_s, dst_s, dist_s,
        Wfn, Wfc, W2f, biasn, biasc, out, xo);
  } else {
    k_pre<false><<<dim3(3297), dim3(256), 0, stream>>>(h, x, out, nullptr, eidx, nullptr,
                                                       Wn1, Wc1, We2, bn1, bc1, be2, Wn2,
                                                       Wfn, Wfc, W2f, biasn, biasc);
    k_main<false><<<dim3(512), dim3(256), 0, stream>>>(
        h, nullptr, x, edist, We1, be1, bn2, Wc2, eidx, nullptr, nullptr, nullptr,
        Wfn, Wfc, W2f, biasn, biasc, out, xo);
  }
}